// Round 11
// baseline (14439.024 us; speedup 1.0000x reference)
//
#include <hip/hip_runtime.h>
#include <stdint.h>

#define BATCH 32
#define M_TOT 3720          // 1000+1000+1000+576+144
#define NCAND 7440          // M_TOT * 2 classes
#define SCORE_THR 0.05f
#define IOU_THR 0.6f
#define RCLIP 4.135166556742356f
#define IMG 1536.0f
#define NTHR 512
#define NOWN 15             // ceil(7440/512) candidates owned per thread
#define KEYS_PER_B 49104    // 36864+9216+2304+576+144

__device__ __forceinline__ float sigf(float x) {
    return __fdiv_rn(1.0f, __fadd_rn(1.0f, expf(-x)));
}

__global__ __launch_bounds__(NTHR) void k_all(
    const float* __restrict__ cls0, const float* __restrict__ bb0, const float* __restrict__ ct0,
    const float* __restrict__ cls1, const float* __restrict__ bb1, const float* __restrict__ ct1,
    const float* __restrict__ cls2, const float* __restrict__ bb2, const float* __restrict__ ct2,
    const float* __restrict__ cls3, const float* __restrict__ bb3, const float* __restrict__ ct3,
    const float* __restrict__ cls4, const float* __restrict__ bb4, const float* __restrict__ ct4,
    float* __restrict__ wkeys, float* __restrict__ out)
{
    __shared__ float s_sc[NCAND];            // live candidate scores (29.8 KB)
    __shared__ unsigned short slots[M_TOT];  // ranked locations        (7.4 KB)
    __shared__ unsigned long long redk[8];
    __shared__ float bc[5];
    __shared__ int bc_pick;

    const int b = blockIdx.x, tid = threadIdx.x;

    const float* CLS[5] = {cls0, cls1, cls2, cls3, cls4};
    const float* BB[5]  = {bb0,  bb1,  bb2,  bb3,  bb4};
    const float* CT[5]  = {ct0,  ct1,  ct2,  ct3,  ct4};
    const int HWs[5]  = {36864, 9216, 2304, 576, 144};
    const int Ws[5]   = {192, 96, 48, 24, 12};
    const int STRs[5] = {8, 16, 32, 64, 128};
    const int MOFF[5] = {0, 1000, 2000, 3000, 3576};
    const int KOFF[5] = {0, 36864, 46080, 48384, 48960};

    float* wkey = wkeys + (size_t)b * KEYS_PER_B;   // block-private key slice

    // -------- Phase 0: pre-NMS keys for all levels --------
    for (int l = 0; l < 5; ++l) {
        const int hw = HWs[l];
        const float* cls = CLS[l];
        const float* ctr = CT[l];
        for (int i = tid; i < hw; i += NTHR) {
            float s0 = sigf(cls[(size_t)(2*b)*hw + i]);
            float s1 = sigf(cls[(size_t)(2*b+1)*hw + i]);
            float sc = sigf(ctr[(size_t)b*hw + i]);
            wkey[KOFF[l] + i] = __fmul_rn(fmaxf(s0, s1), sc);   // > 0 always
        }
    }
    __syncthreads();

    // -------- Phase 1: LITERAL lax.top_k — repeated argmax w/ invalidation --
    // argmax = max value, tie -> lowest index; rank r stored at slots[MOFF+r].
    for (int l = 0; l < 5; ++l) {
        const int hw = HWs[l];
        const int off = KOFF[l];
        const int take = (hw < 1000) ? hw : 1000;
        for (int r = 0; r < take; ++r) {
            unsigned long long lkey = 0;
            for (int i = tid; i < hw; i += NTHR) {
                float sv = wkey[off + i];
                if (sv > 0.0f) {
                    unsigned long long key =
                        (((unsigned long long)__float_as_uint(sv)) << 20) | (unsigned)(0xFFFFF - i);
                    lkey = (key > lkey) ? key : lkey;
                }
            }
            for (int d = 32; d >= 1; d >>= 1) {
                unsigned long long o = __shfl_down(lkey, d);
                lkey = (o > lkey) ? o : lkey;
            }
            if ((tid & 63) == 0) redk[tid >> 6] = lkey;
            __syncthreads();
            if (tid == 0) {
                unsigned long long m0 = redk[0];
                for (int q = 1; q < 8; ++q) m0 = (redk[q] > m0) ? redk[q] : m0;
                int ip = (int)(0xFFFFFu - (unsigned)(m0 & 0xFFFFFu));
                slots[MOFF[l] + r] = (unsigned short)ip;
                wkey[off + ip] = -1.0f;          // invalidate for next rank
            }
            __syncthreads();
        }
    }

    // -------- Phase 2: candidate scores (LDS) + box decode (registers) -----
    float cx1[NOWN], cy1[NOWN], cx2[NOWN], cy2[NOWN];
#pragma unroll
    for (int k = 0; k < NOWN; ++k) {
        int j = k * NTHR + tid;
        if (j < NCAND) {
            int m = j >> 1, c = j & 1;
            int l;
            if (m < 1000)      l = 0;
            else if (m < 2000) l = 1;
            else if (m < 3000) l = 2;
            else if (m < 3576) l = 3;
            else               l = 4;
            const int hw = HWs[l], w = Ws[l], stride = STRs[l];
            int loc = slots[m];
            float sc = __fmul_rn(sigf(CLS[l][(size_t)(2*b + c)*hw + loc]),
                                 sigf(CT[l][(size_t)b*hw + loc]));
            s_sc[j] = (sc > SCORE_THR) ? sc : -1.0f;

            int yy = loc / w;
            int xx = loc - yy * w;
            const float* bb = BB[l];
            float d0 = bb[(size_t)(4*b+0)*hw + loc];
            float d1 = bb[(size_t)(4*b+1)*hw + loc];
            float d2 = bb[(size_t)(4*b+2)*hw + loc];
            float d3 = bb[(size_t)(4*b+3)*hw + loc];
            float a   = (float)(8 * stride);
            float acx = (float)(xx * stride);
            float acy = (float)(yy * stride);
            float dwv = fminf(fmaxf(d2, -RCLIP), RCLIP);
            float dhv = fminf(fmaxf(d3, -RCLIP), RCLIP);
            float pcx = __fadd_rn(acx, __fmul_rn(d0, a));
            float pcy = __fadd_rn(acy, __fmul_rn(d1, a));
            float pw  = __fmul_rn(a, expf(dwv));
            float ph  = __fmul_rn(a, expf(dhv));
            cx1[k] = fminf(fmaxf(__fsub_rn(pcx, __fmul_rn(0.5f, pw)), 0.0f), IMG);
            cy1[k] = fminf(fmaxf(__fsub_rn(pcy, __fmul_rn(0.5f, ph)), 0.0f), IMG);
            cx2[k] = fminf(fmaxf(__fadd_rn(pcx, __fmul_rn(0.5f, pw)), 0.0f), IMG);
            cy2[k] = fminf(fmaxf(__fadd_rn(pcy, __fmul_rn(0.5f, ph)), 0.0f), IMG);
        }
    }
    __syncthreads();

    // -------- Phase 3: LITERAL greedy NMS — 100 argmax+suppress iterations --
    const float myoff = (tid & 1) ? (IMG + 1.0f) : 0.0f;   // j&1 == tid&1
    for (int t = 0; t < 100; ++t) {
        unsigned long long lkey = 0;
#pragma unroll
        for (int k = 0; k < NOWN; ++k) {
            int j = k * NTHR + tid;
            if (j < NCAND) {
                float sv = s_sc[j];
                if (sv > 0.0f) {
                    unsigned long long key =
                        (((unsigned long long)__float_as_uint(sv)) << 20) | (unsigned)(0xFFFFF - j);
                    lkey = (key > lkey) ? key : lkey;
                }
            }
        }
        for (int d = 32; d >= 1; d >>= 1) {
            unsigned long long o = __shfl_down(lkey, d);
            lkey = (o > lkey) ? o : lkey;
        }
        if ((tid & 63) == 0) redk[tid >> 6] = lkey;
        __syncthreads();
        if (tid == 0) {
            unsigned long long m0 = redk[0];
            for (int q = 1; q < 8; ++q) m0 = (redk[q] > m0) ? redk[q] : m0;
            int ip = (m0 == 0ULL) ? -1 : (int)(0xFFFFFu - (unsigned)(m0 & 0xFFFFFu));
            bc_pick = ip;
            bc[4] = (ip >= 0) ? s_sc[ip] : -1.0f;
        }
        __syncthreads();
        const int ipick = bc_pick;
        if (ipick >= 0) {
#pragma unroll
            for (int k = 0; k < NOWN; ++k) {
                int j = k * NTHR + tid;
                if (j == ipick) { bc[0]=cx1[k]; bc[1]=cy1[k]; bc[2]=cx2[k]; bc[3]=cy2[k]; }
            }
        }
        __syncthreads();
        if (ipick >= 0) {
            const float offi = (ipick & 1) ? (IMG + 1.0f) : 0.0f;
            const float px1 = __fadd_rn(bc[0], offi), py1 = __fadd_rn(bc[1], offi);
            const float px2 = __fadd_rn(bc[2], offi), py2 = __fadd_rn(bc[3], offi);
            const float pa  = __fmul_rn(__fsub_rn(px2, px1), __fsub_rn(py2, py1));
            if (((tid ^ ipick) & 1) == 0) {   // cross-class iou == 0 always
#pragma unroll
                for (int k = 0; k < NOWN; ++k) {
                    int j = k * NTHR + tid;
                    if (j < NCAND) {
                        float ox1 = __fadd_rn(cx1[k], myoff), oy1 = __fadd_rn(cy1[k], myoff);
                        float ox2 = __fadd_rn(cx2[k], myoff), oy2 = __fadd_rn(cy2[k], myoff);
                        float ca  = __fmul_rn(__fsub_rn(ox2, ox1), __fsub_rn(oy2, oy1));
                        float ix1 = fmaxf(px1, ox1), iy1 = fmaxf(py1, oy1);
                        float ix2 = fminf(px2, ox2), iy2 = fminf(py2, oy2);
                        float inter = __fmul_rn(fmaxf(__fsub_rn(ix2, ix1), 0.0f),
                                                fmaxf(__fsub_rn(iy2, iy1), 0.0f));
                        float uni = fmaxf(__fsub_rn(__fadd_rn(pa, ca), inter), 1e-6f);
                        if (__fdiv_rn(inter, uni) > IOU_THR) s_sc[j] = -1.0f;
                    }
                }
            }
        }
        if (tid == 0) {
            // FP32 output: dets [B,100,5] at [0:16000), labels [B,100] at [16000:19200)
            float* dr = out + ((size_t)b * 100 + t) * 5;
            if (ipick >= 0) {
                dr[0] = bc[0]; dr[1] = bc[1]; dr[2] = bc[2]; dr[3] = bc[3]; dr[4] = bc[4];
                out[(size_t)BATCH * 500 + b * 100 + t] = (float)(ipick & 1);
            } else {
                dr[0] = 0.0f; dr[1] = 0.0f; dr[2] = 0.0f; dr[3] = 0.0f; dr[4] = 0.0f;
                out[(size_t)BATCH * 500 + b * 100 + t] = -1.0f;
            }
        }
        __syncthreads();
    }
}

extern "C" void kernel_launch(void* const* d_in, const int* in_sizes, int n_in,
                              void* d_out, int out_size, void* d_ws, size_t ws_size,
                              hipStream_t stream) {
    static const int HW5[5] = {36864, 9216, 2304, 576, 144};
    int mc[5], mb[5], mt[5];
    bool found = false;
    for (int hyp = 0; hyp < 3 && !found; ++hyp) {
        bool ok = true;
        int tc[5], tb[5], tt[5];
        for (int l = 0; l < 5 && ok; ++l) {
            int ic, ib, it;
            if (hyp == 0)      { ic = 3*l;   ib = 3*l+1; it = 3*l+2; } // dict order
            else if (hyp == 1) { ic = l;     ib = 5+l;   it = 10+l;  } // arg order
            else               { ib = l;     ic = 5+l;   it = 10+l;  } // sorted keys
            if (in_sizes[ic] != 2*BATCH*HW5[l] ||
                in_sizes[ib] != 4*BATCH*HW5[l] ||
                in_sizes[it] != 1*BATCH*HW5[l]) ok = false;
            tc[l]=ic; tb[l]=ib; tt[l]=it;
        }
        if (ok) { for (int l=0;l<5;++l){mc[l]=tc[l];mb[l]=tb[l];mt[l]=tt[l];} found = true; }
    }
    if (!found) { for (int l=0;l<5;++l){mc[l]=3*l;mb[l]=3*l+1;mt[l]=3*l+2;} }

    const float* C[5]; const float* Bb[5]; const float* T[5];
    for (int l = 0; l < 5; ++l) {
        C[l]  = (const float*)d_in[mc[l]];
        Bb[l] = (const float*)d_in[mb[l]];
        T[l]  = (const float*)d_in[mt[l]];
    }

    float* wkeys = (float*)d_ws;   // BATCH * 49104 * 4 B = 6.3 MB

    k_all<<<dim3(BATCH), dim3(NTHR), 0, stream>>>(
        C[0], Bb[0], T[0], C[1], Bb[1], T[1], C[2], Bb[2], T[2],
        C[3], Bb[3], T[3], C[4], Bb[4], T[4], wkeys, (float*)d_out);
}

// Round 12
// 917.693 us; speedup vs baseline: 15.7340x; 15.7340x over previous
//
#include <hip/hip_runtime.h>
#include <stdint.h>

#define BATCH 32
#define M_TOT 3720          // 1000+1000+1000+576+144
#define NCAND 7440          // M_TOT * 2 classes
#define SCORE_THR 0.05f
#define IOU_THR 0.6f
#define RCLIP 4.135166556742356f
#define IMG 1536.0f
#define NTHR 512
#define NOWN 15             // ceil(7440/512) candidates owned per thread
#define KEYS_PER_B 49104    // 36864+9216+2304+576+144

__device__ __forceinline__ float sigf(float x) {
    return __fdiv_rn(1.0f, __fadd_rn(1.0f, expf(-x)));
}

__global__ __launch_bounds__(NTHR) void k_all(
    const float* __restrict__ cls0, const float* __restrict__ bb0, const float* __restrict__ ct0,
    const float* __restrict__ cls1, const float* __restrict__ bb1, const float* __restrict__ ct1,
    const float* __restrict__ cls2, const float* __restrict__ bb2, const float* __restrict__ ct2,
    const float* __restrict__ cls3, const float* __restrict__ bb3, const float* __restrict__ ct3,
    const float* __restrict__ cls4, const float* __restrict__ bb4, const float* __restrict__ ct4,
    float* __restrict__ wkeys, float* __restrict__ out)
{
    __shared__ float s_sc[NCAND];            // 29.8 KB live candidate scores
    __shared__ unsigned short slots[M_TOT];  //  7.4 KB ranked locations
    __shared__ unsigned long long cu[2048];  // 16.0 KB compacted composites
    __shared__ unsigned hist[256];           //  1.0 KB radix histogram
    __shared__ unsigned long long redk[8];
    __shared__ float bc[5];
    __shared__ int bc_pick;
    __shared__ unsigned sh_bin, sh_krem, sh_cnt;

    const int b = blockIdx.x, tid = threadIdx.x;

    const float* CLS[5] = {cls0, cls1, cls2, cls3, cls4};
    const float* BB[5]  = {bb0,  bb1,  bb2,  bb3,  bb4};
    const float* CT[5]  = {ct0,  ct1,  ct2,  ct3,  ct4};
    const int HWs[5]  = {36864, 9216, 2304, 576, 144};
    const int Ws[5]   = {192, 96, 48, 24, 12};
    const int STRs[5] = {8, 16, 32, 64, 128};
    const int MOFF[5] = {0, 1000, 2000, 3000, 3576};
    const int KOFF[5] = {0, 36864, 46080, 48384, 48960};

    float* wkey = wkeys + (size_t)b * KEYS_PER_B;   // block-private key slice

    // -------- Phase 0: pre-NMS keys for all levels (unchanged, green) ------
    for (int l = 0; l < 5; ++l) {
        const int hw = HWs[l];
        const float* cls = CLS[l];
        const float* ctr = CT[l];
        for (int i = tid; i < hw; i += NTHR) {
            float s0 = sigf(cls[(size_t)(2*b)*hw + i]);
            float s1 = sigf(cls[(size_t)(2*b+1)*hw + i]);
            float sc = sigf(ctr[(size_t)b*hw + i]);
            wkey[KOFF[l] + i] = __fmul_rn(fmaxf(s0, s1), sc);   // > 0 always
        }
    }
    __syncthreads();

    // -------- Phase 1: exact top-k rank order via radix-select + rank-count -
    // Semantics identical to lax.top_k: order by (value desc, loc asc),
    // value ties counted with multiplicity (krem accounting).
    for (int l = 0; l < 5; ++l) {
        const int hw = HWs[l];
        const int off = KOFF[l];
        const int take = (hw < 1000) ? hw : 1000;
        int n;
        if (hw > 1000) {
            // 4-pass radix-select: exact fp32 bits T of the 1000th-largest key
            unsigned pref = 0, krem = 1000;
            for (int p = 0; p < 4; ++p) {
                const int shift = 24 - 8 * p;
                if (tid < 256) hist[tid] = 0;
                __syncthreads();
                for (int i = tid; i < hw; i += NTHR) {
                    unsigned u = __float_as_uint(wkey[off + i]);
                    bool match = (p == 0) || ((u >> (shift + 8)) == pref);
                    if (match) atomicAdd(&hist[(u >> shift) & 255u], 1u);
                }
                __syncthreads();
                if (tid == 0) {
                    unsigned c = 0; int bsel = 0; unsigned kr = krem;
                    for (int bin = 255; bin >= 0; --bin) {
                        unsigned h = hist[bin];
                        if (c + h >= kr) { bsel = bin; kr -= c; break; }
                        c += h;
                    }
                    sh_bin = (unsigned)bsel;
                    sh_krem = kr;
                    sh_cnt = 0;
                }
                __syncthreads();
                pref = (pref << 8) | sh_bin;
                krem = sh_krem;
            }
            const unsigned T = pref;
            // compact u >= T (superset of rank-top-1000; n in [1000, ~1005])
            for (int i = tid; i < hw; i += NTHR) {
                unsigned u = __float_as_uint(wkey[off + i]);
                if (u >= T) {
                    unsigned pos = atomicAdd(&sh_cnt, 1u);
                    if (pos < 2048u)
                        cu[pos] = (((unsigned long long)u) << 20) | (unsigned)(0xFFFFF - i);
                }
            }
            __syncthreads();
            n = (int)sh_cnt; if (n > 2048) n = 2048;
        } else {
            for (int i = tid; i < hw; i += NTHR) {
                unsigned u = __float_as_uint(wkey[off + i]);
                cu[i] = (((unsigned long long)u) << 20) | (unsigned)(0xFFFFF - i);
            }
            n = hw;
            __syncthreads();
        }
        // rank-by-count: rank = #entries with strictly larger composite.
        // Composite order == (value desc, loc asc); entries unique (loc unique).
        for (int a = tid; a < n; a += NTHR) {
            unsigned long long ka = cu[a];
            int rank = 0;
            for (int q = 0; q < n; ++q) rank += (cu[q] > ka) ? 1 : 0;
            if (rank < take) {
                unsigned loc = 0xFFFFFu - (unsigned)(ka & 0xFFFFFu);
                slots[MOFF[l] + rank] = (unsigned short)loc;
            }
        }
        __syncthreads();
    }

    // -------- Phase 2: candidate scores (LDS) + box decode (registers) -----
    float cx1[NOWN], cy1[NOWN], cx2[NOWN], cy2[NOWN];
#pragma unroll
    for (int k = 0; k < NOWN; ++k) {
        int j = k * NTHR + tid;
        if (j < NCAND) {
            int m = j >> 1, c = j & 1;
            int l;
            if (m < 1000)      l = 0;
            else if (m < 2000) l = 1;
            else if (m < 3000) l = 2;
            else if (m < 3576) l = 3;
            else               l = 4;
            const int hw = HWs[l], w = Ws[l], stride = STRs[l];
            int loc = slots[m];
            float sc = __fmul_rn(sigf(CLS[l][(size_t)(2*b + c)*hw + loc]),
                                 sigf(CT[l][(size_t)b*hw + loc]));
            s_sc[j] = (sc > SCORE_THR) ? sc : -1.0f;

            int yy = loc / w;
            int xx = loc - yy * w;
            const float* bb = BB[l];
            float d0 = bb[(size_t)(4*b+0)*hw + loc];
            float d1 = bb[(size_t)(4*b+1)*hw + loc];
            float d2 = bb[(size_t)(4*b+2)*hw + loc];
            float d3 = bb[(size_t)(4*b+3)*hw + loc];
            float a   = (float)(8 * stride);
            float acx = (float)(xx * stride);
            float acy = (float)(yy * stride);
            float dwv = fminf(fmaxf(d2, -RCLIP), RCLIP);
            float dhv = fminf(fmaxf(d3, -RCLIP), RCLIP);
            float pcx = __fadd_rn(acx, __fmul_rn(d0, a));
            float pcy = __fadd_rn(acy, __fmul_rn(d1, a));
            float pw  = __fmul_rn(a, expf(dwv));
            float ph  = __fmul_rn(a, expf(dhv));
            cx1[k] = fminf(fmaxf(__fsub_rn(pcx, __fmul_rn(0.5f, pw)), 0.0f), IMG);
            cy1[k] = fminf(fmaxf(__fsub_rn(pcy, __fmul_rn(0.5f, ph)), 0.0f), IMG);
            cx2[k] = fminf(fmaxf(__fadd_rn(pcx, __fmul_rn(0.5f, pw)), 0.0f), IMG);
            cy2[k] = fminf(fmaxf(__fadd_rn(pcy, __fmul_rn(0.5f, ph)), 0.0f), IMG);
        }
    }
    __syncthreads();

    // -------- Phase 3: LITERAL greedy NMS (unchanged, green) ---------------
    const float myoff = (tid & 1) ? (IMG + 1.0f) : 0.0f;   // j&1 == tid&1
    for (int t = 0; t < 100; ++t) {
        unsigned long long lkey = 0;
#pragma unroll
        for (int k = 0; k < NOWN; ++k) {
            int j = k * NTHR + tid;
            if (j < NCAND) {
                float sv = s_sc[j];
                if (sv > 0.0f) {
                    unsigned long long key =
                        (((unsigned long long)__float_as_uint(sv)) << 20) | (unsigned)(0xFFFFF - j);
                    lkey = (key > lkey) ? key : lkey;
                }
            }
        }
        for (int d = 32; d >= 1; d >>= 1) {
            unsigned long long o = __shfl_down(lkey, d);
            lkey = (o > lkey) ? o : lkey;
        }
        if ((tid & 63) == 0) redk[tid >> 6] = lkey;
        __syncthreads();
        if (tid == 0) {
            unsigned long long m0 = redk[0];
            for (int q = 1; q < 8; ++q) m0 = (redk[q] > m0) ? redk[q] : m0;
            int ip = (m0 == 0ULL) ? -1 : (int)(0xFFFFFu - (unsigned)(m0 & 0xFFFFFu));
            bc_pick = ip;
            bc[4] = (ip >= 0) ? s_sc[ip] : -1.0f;
        }
        __syncthreads();
        const int ipick = bc_pick;
        if (ipick >= 0) {
#pragma unroll
            for (int k = 0; k < NOWN; ++k) {
                int j = k * NTHR + tid;
                if (j == ipick) { bc[0]=cx1[k]; bc[1]=cy1[k]; bc[2]=cx2[k]; bc[3]=cy2[k]; }
            }
        }
        __syncthreads();
        if (ipick >= 0) {
            const float offi = (ipick & 1) ? (IMG + 1.0f) : 0.0f;
            const float px1 = __fadd_rn(bc[0], offi), py1 = __fadd_rn(bc[1], offi);
            const float px2 = __fadd_rn(bc[2], offi), py2 = __fadd_rn(bc[3], offi);
            const float pa  = __fmul_rn(__fsub_rn(px2, px1), __fsub_rn(py2, py1));
            if (((tid ^ ipick) & 1) == 0) {   // cross-class iou == 0 always
#pragma unroll
                for (int k = 0; k < NOWN; ++k) {
                    int j = k * NTHR + tid;
                    if (j < NCAND) {
                        float ox1 = __fadd_rn(cx1[k], myoff), oy1 = __fadd_rn(cy1[k], myoff);
                        float ox2 = __fadd_rn(cx2[k], myoff), oy2 = __fadd_rn(cy2[k], myoff);
                        float ca  = __fmul_rn(__fsub_rn(ox2, ox1), __fsub_rn(oy2, oy1));
                        float ix1 = fmaxf(px1, ox1), iy1 = fmaxf(py1, oy1);
                        float ix2 = fminf(px2, ox2), iy2 = fminf(py2, oy2);
                        float inter = __fmul_rn(fmaxf(__fsub_rn(ix2, ix1), 0.0f),
                                                fmaxf(__fsub_rn(iy2, iy1), 0.0f));
                        float uni = fmaxf(__fsub_rn(__fadd_rn(pa, ca), inter), 1e-6f);
                        if (__fdiv_rn(inter, uni) > IOU_THR) s_sc[j] = -1.0f;
                    }
                }
            }
        }
        if (tid == 0) {
            float* dr = out + ((size_t)b * 100 + t) * 5;
            if (ipick >= 0) {
                dr[0] = bc[0]; dr[1] = bc[1]; dr[2] = bc[2]; dr[3] = bc[3]; dr[4] = bc[4];
                out[(size_t)BATCH * 500 + b * 100 + t] = (float)(ipick & 1);
            } else {
                dr[0] = 0.0f; dr[1] = 0.0f; dr[2] = 0.0f; dr[3] = 0.0f; dr[4] = 0.0f;
                out[(size_t)BATCH * 500 + b * 100 + t] = -1.0f;
            }
        }
        __syncthreads();
    }
}

extern "C" void kernel_launch(void* const* d_in, const int* in_sizes, int n_in,
                              void* d_out, int out_size, void* d_ws, size_t ws_size,
                              hipStream_t stream) {
    static const int HW5[5] = {36864, 9216, 2304, 576, 144};
    int mc[5], mb[5], mt[5];
    bool found = false;
    for (int hyp = 0; hyp < 3 && !found; ++hyp) {
        bool ok = true;
        int tc[5], tb[5], tt[5];
        for (int l = 0; l < 5 && ok; ++l) {
            int ic, ib, it;
            if (hyp == 0)      { ic = 3*l;   ib = 3*l+1; it = 3*l+2; } // dict order
            else if (hyp == 1) { ic = l;     ib = 5+l;   it = 10+l;  } // arg order
            else               { ib = l;     ic = 5+l;   it = 10+l;  } // sorted keys
            if (in_sizes[ic] != 2*BATCH*HW5[l] ||
                in_sizes[ib] != 4*BATCH*HW5[l] ||
                in_sizes[it] != 1*BATCH*HW5[l]) ok = false;
            tc[l]=ic; tb[l]=ib; tt[l]=it;
        }
        if (ok) { for (int l=0;l<5;++l){mc[l]=tc[l];mb[l]=tb[l];mt[l]=tt[l];} found = true; }
    }
    if (!found) { for (int l=0;l<5;++l){mc[l]=3*l;mb[l]=3*l+1;mt[l]=3*l+2;} }

    const float* C[5]; const float* Bb[5]; const float* T[5];
    for (int l = 0; l < 5; ++l) {
        C[l]  = (const float*)d_in[mc[l]];
        Bb[l] = (const float*)d_in[mb[l]];
        T[l]  = (const float*)d_in[mt[l]];
    }

    float* wkeys = (float*)d_ws;   // BATCH * 49104 * 4 B = 6.3 MB

    k_all<<<dim3(BATCH), dim3(NTHR), 0, stream>>>(
        C[0], Bb[0], T[0], C[1], Bb[1], T[1], C[2], Bb[2], T[2],
        C[3], Bb[3], T[3], C[4], Bb[4], T[4], wkeys, (float*)d_out);
}

// Round 13
// 501.648 us; speedup vs baseline: 28.7832x; 1.8294x over previous
//
#include <hip/hip_runtime.h>
#include <stdint.h>

#define BATCH 32
#define M_TOT 3720          // 1000+1000+1000+576+144
#define NCAND 7440          // M_TOT * 2 classes
#define SCORE_THR 0.05f
#define IOU_THR 0.6f
#define RCLIP 4.135166556742356f
#define IMG 1536.0f
#define KEYS_PER_B 49104    // 36864+9216+2304+576+144
#define NTHR_NMS 512
#define NOWN 15             // ceil(7440/512)

__device__ __forceinline__ float sigf(float x) {
    return __fdiv_rn(1.0f, __fadd_rn(1.0f, expf(-x)));
}

__device__ __forceinline__ int lvl_of_i(int i, int& loc) {
    if (i < 36864)      { loc = i;         return 0; }
    else if (i < 46080) { loc = i - 36864; return 1; }
    else if (i < 48384) { loc = i - 46080; return 2; }
    else if (i < 48960) { loc = i - 48384; return 3; }
    else                { loc = i - 48960; return 4; }
}

struct P5 { const float* p[5]; };

// ---------- K0: pre-NMS keys, wide ----------
__global__ __launch_bounds__(256) void k_keys(P5 CLS, P5 CT, float* __restrict__ wkeys) {
    const int HWs[5] = {36864, 9216, 2304, 576, 144};
    const int total = BATCH * KEYS_PER_B;
    for (int t = blockIdx.x * blockDim.x + threadIdx.x; t < total;
         t += gridDim.x * blockDim.x) {
        int b = t / KEYS_PER_B;
        int i = t - b * KEYS_PER_B;
        int loc; int l = lvl_of_i(i, loc);
        int hw = HWs[l];
        float s0 = sigf(CLS.p[l][(size_t)(2*b)*hw + loc]);
        float s1 = sigf(CLS.p[l][(size_t)(2*b+1)*hw + loc]);
        float sc = sigf(CT.p[l][(size_t)b*hw + loc]);
        wkeys[t] = __fmul_rn(fmaxf(s0, s1), sc);   // > 0 always
    }
}

// ---------- K1: per-(b,l) exact top-k rank order (radix + rank-count) ------
__global__ __launch_bounds__(512) void k_select(const float* __restrict__ wkeys,
                                                unsigned short* __restrict__ slots_g) {
    __shared__ unsigned long long cu[2048];   // 16 KB composites
    __shared__ unsigned hist[256];
    __shared__ unsigned sh_bin, sh_krem, sh_cnt;

    const int HWs[5]  = {36864, 9216, 2304, 576, 144};
    const int MOFF[5] = {0, 1000, 2000, 3000, 3576};
    const int KOFF[5] = {0, 36864, 46080, 48384, 48960};

    const int blk = blockIdx.x;        // 0..159
    const int b = blk / 5, l = blk % 5;
    const int tid = threadIdx.x;
    const int hw = HWs[l];
    const int take = (hw < 1000) ? hw : 1000;
    const float* wkey = wkeys + (size_t)b * KEYS_PER_B + KOFF[l];

    int n;
    if (hw > 1000) {
        // 4-pass radix-select: exact fp32 bits T of the 1000th-largest key
        unsigned pref = 0, krem = 1000;
        for (int p = 0; p < 4; ++p) {
            const int shift = 24 - 8 * p;
            if (tid < 256) hist[tid] = 0;
            __syncthreads();
            for (int i = tid; i < hw; i += 512) {
                unsigned u = __float_as_uint(wkey[i]);
                bool match = (p == 0) || ((u >> (shift + 8)) == pref);
                if (match) atomicAdd(&hist[(u >> shift) & 255u], 1u);
            }
            __syncthreads();
            if (tid == 0) {
                unsigned c = 0; int bsel = 0; unsigned kr = krem;
                for (int bin = 255; bin >= 0; --bin) {
                    unsigned h = hist[bin];
                    if (c + h >= kr) { bsel = bin; kr -= c; break; }
                    c += h;
                }
                sh_bin = (unsigned)bsel;
                sh_krem = kr;
                sh_cnt = 0;
            }
            __syncthreads();
            pref = (pref << 8) | sh_bin;
            krem = sh_krem;
        }
        const unsigned T = pref;
        for (int i = tid; i < hw; i += 512) {
            unsigned u = __float_as_uint(wkey[i]);
            if (u >= T) {
                unsigned pos = atomicAdd(&sh_cnt, 1u);
                if (pos < 2048u)
                    cu[pos] = (((unsigned long long)u) << 20) | (unsigned)(0xFFFFF - i);
            }
        }
        __syncthreads();
        n = (int)sh_cnt; if (n > 2048) n = 2048;
    } else {
        for (int i = tid; i < hw; i += 512) {
            unsigned u = __float_as_uint(wkey[i]);
            cu[i] = (((unsigned long long)u) << 20) | (unsigned)(0xFFFFF - i);
        }
        n = hw;
        __syncthreads();
    }
    // rank-by-count (composite order == value desc, loc asc; entries unique)
    for (int a = tid; a < n; a += 512) {
        unsigned long long ka = cu[a];
        int rank = 0;
        for (int q = 0; q < n; ++q) rank += (cu[q] > ka) ? 1 : 0;
        if (rank < take) {
            unsigned loc = 0xFFFFFu - (unsigned)(ka & 0xFFFFFu);
            slots_g[(size_t)b * M_TOT + MOFF[l] + rank] = (unsigned short)loc;
        }
    }
}

// ---------- K2: decode boxes + candidate scores, wide ----------------------
__global__ __launch_bounds__(256) void k_decode(P5 CLS, P5 BB, P5 CT,
                                                const unsigned short* __restrict__ slots_g,
                                                float* __restrict__ boxes_g,
                                                float* __restrict__ scores_g) {
    const int HWs[5]  = {36864, 9216, 2304, 576, 144};
    const int Ws[5]   = {192, 96, 48, 24, 12};
    const int STRs[5] = {8, 16, 32, 64, 128};
    int t = blockIdx.x * blockDim.x + threadIdx.x;
    if (t >= BATCH * M_TOT) return;
    int b = t / M_TOT;
    int m = t - b * M_TOT;
    int l;
    if (m < 1000)      l = 0;
    else if (m < 2000) l = 1;
    else if (m < 3000) l = 2;
    else if (m < 3576) l = 3;
    else               l = 4;
    const int hw = HWs[l], w = Ws[l], stride = STRs[l];
    int loc = slots_g[t];

    float ctv = sigf(CT.p[l][(size_t)b*hw + loc]);
    float sc0 = __fmul_rn(sigf(CLS.p[l][(size_t)(2*b+0)*hw + loc]), ctv);
    float sc1 = __fmul_rn(sigf(CLS.p[l][(size_t)(2*b+1)*hw + loc]), ctv);
    scores_g[(size_t)b * NCAND + 2*m + 0] = (sc0 > SCORE_THR) ? sc0 : -1.0f;
    scores_g[(size_t)b * NCAND + 2*m + 1] = (sc1 > SCORE_THR) ? sc1 : -1.0f;

    int yy = loc / w;
    int xx = loc - yy * w;
    const float* bb = BB.p[l];
    float d0 = bb[(size_t)(4*b+0)*hw + loc];
    float d1 = bb[(size_t)(4*b+1)*hw + loc];
    float d2 = bb[(size_t)(4*b+2)*hw + loc];
    float d3 = bb[(size_t)(4*b+3)*hw + loc];
    float a   = (float)(8 * stride);
    float acx = (float)(xx * stride);
    float acy = (float)(yy * stride);
    float dwv = fminf(fmaxf(d2, -RCLIP), RCLIP);
    float dhv = fminf(fmaxf(d3, -RCLIP), RCLIP);
    float pcx = __fadd_rn(acx, __fmul_rn(d0, a));
    float pcy = __fadd_rn(acy, __fmul_rn(d1, a));
    float pw  = __fmul_rn(a, expf(dwv));
    float ph  = __fmul_rn(a, expf(dhv));
    float* bx = boxes_g + (size_t)t * 4;
    bx[0] = fminf(fmaxf(__fsub_rn(pcx, __fmul_rn(0.5f, pw)), 0.0f), IMG);
    bx[1] = fminf(fmaxf(__fsub_rn(pcy, __fmul_rn(0.5f, ph)), 0.0f), IMG);
    bx[2] = fminf(fmaxf(__fadd_rn(pcx, __fmul_rn(0.5f, pw)), 0.0f), IMG);
    bx[3] = fminf(fmaxf(__fadd_rn(pcy, __fmul_rn(0.5f, ph)), 0.0f), IMG);
}

// ---------- K3: LITERAL greedy NMS per batch (green, unchanged math) -------
__global__ __launch_bounds__(NTHR_NMS) void k_nms(const float* __restrict__ boxes_g,
                                                  const float* __restrict__ scores_g,
                                                  float* __restrict__ out) {
    __shared__ float s_sc[NCAND];            // 29.8 KB live candidate scores
    __shared__ unsigned long long redk[8];
    __shared__ float bc[5];
    __shared__ int bc_pick;

    const int b = blockIdx.x, tid = threadIdx.x;
    const float* bxg = boxes_g + (size_t)b * M_TOT * 4;

    float cx1[NOWN], cy1[NOWN], cx2[NOWN], cy2[NOWN];
#pragma unroll
    for (int k = 0; k < NOWN; ++k) {
        int j = k * NTHR_NMS + tid;
        if (j < NCAND) {
            s_sc[j] = scores_g[(size_t)b * NCAND + j];
            const float* p = bxg + (size_t)(j >> 1) * 4;
            cx1[k] = p[0]; cy1[k] = p[1]; cx2[k] = p[2]; cy2[k] = p[3];
        }
    }
    __syncthreads();

    const float myoff = (tid & 1) ? (IMG + 1.0f) : 0.0f;   // j&1 == tid&1
    for (int t = 0; t < 100; ++t) {
        unsigned long long lkey = 0;
#pragma unroll
        for (int k = 0; k < NOWN; ++k) {
            int j = k * NTHR_NMS + tid;
            if (j < NCAND) {
                float sv = s_sc[j];
                if (sv > 0.0f) {
                    unsigned long long key =
                        (((unsigned long long)__float_as_uint(sv)) << 20) | (unsigned)(0xFFFFF - j);
                    lkey = (key > lkey) ? key : lkey;
                }
            }
        }
        for (int d = 32; d >= 1; d >>= 1) {
            unsigned long long o = __shfl_down(lkey, d);
            lkey = (o > lkey) ? o : lkey;
        }
        if ((tid & 63) == 0) redk[tid >> 6] = lkey;
        __syncthreads();
        if (tid == 0) {
            unsigned long long m0 = redk[0];
            for (int q = 1; q < 8; ++q) m0 = (redk[q] > m0) ? redk[q] : m0;
            int ip = (m0 == 0ULL) ? -1 : (int)(0xFFFFFu - (unsigned)(m0 & 0xFFFFFu));
            bc_pick = ip;
            bc[4] = (ip >= 0) ? s_sc[ip] : -1.0f;
        }
        __syncthreads();
        const int ipick = bc_pick;
        if (ipick >= 0) {
#pragma unroll
            for (int k = 0; k < NOWN; ++k) {
                int j = k * NTHR_NMS + tid;
                if (j == ipick) { bc[0]=cx1[k]; bc[1]=cy1[k]; bc[2]=cx2[k]; bc[3]=cy2[k]; }
            }
        }
        __syncthreads();
        if (ipick >= 0) {
            const float offi = (ipick & 1) ? (IMG + 1.0f) : 0.0f;
            const float px1 = __fadd_rn(bc[0], offi), py1 = __fadd_rn(bc[1], offi);
            const float px2 = __fadd_rn(bc[2], offi), py2 = __fadd_rn(bc[3], offi);
            const float pa  = __fmul_rn(__fsub_rn(px2, px1), __fsub_rn(py2, py1));
            if (((tid ^ ipick) & 1) == 0) {   // cross-class iou == 0 always
#pragma unroll
                for (int k = 0; k < NOWN; ++k) {
                    int j = k * NTHR_NMS + tid;
                    if (j < NCAND) {
                        float ox1 = __fadd_rn(cx1[k], myoff), oy1 = __fadd_rn(cy1[k], myoff);
                        float ox2 = __fadd_rn(cx2[k], myoff), oy2 = __fadd_rn(cy2[k], myoff);
                        float ca  = __fmul_rn(__fsub_rn(ox2, ox1), __fsub_rn(oy2, oy1));
                        float ix1 = fmaxf(px1, ox1), iy1 = fmaxf(py1, oy1);
                        float ix2 = fminf(px2, ox2), iy2 = fminf(py2, oy2);
                        float inter = __fmul_rn(fmaxf(__fsub_rn(ix2, ix1), 0.0f),
                                                fmaxf(__fsub_rn(iy2, iy1), 0.0f));
                        float uni = fmaxf(__fsub_rn(__fadd_rn(pa, ca), inter), 1e-6f);
                        if (__fdiv_rn(inter, uni) > IOU_THR) s_sc[j] = -1.0f;
                    }
                }
            }
        }
        if (tid == 0) {
            float* dr = out + ((size_t)b * 100 + t) * 5;
            if (ipick >= 0) {
                dr[0] = bc[0]; dr[1] = bc[1]; dr[2] = bc[2]; dr[3] = bc[3]; dr[4] = bc[4];
                out[(size_t)BATCH * 500 + b * 100 + t] = (float)(ipick & 1);
            } else {
                dr[0] = 0.0f; dr[1] = 0.0f; dr[2] = 0.0f; dr[3] = 0.0f; dr[4] = 0.0f;
                out[(size_t)BATCH * 500 + b * 100 + t] = -1.0f;
            }
        }
        __syncthreads();
    }
}

extern "C" void kernel_launch(void* const* d_in, const int* in_sizes, int n_in,
                              void* d_out, int out_size, void* d_ws, size_t ws_size,
                              hipStream_t stream) {
    static const int HW5[5] = {36864, 9216, 2304, 576, 144};
    int mc[5], mb[5], mt[5];
    bool found = false;
    for (int hyp = 0; hyp < 3 && !found; ++hyp) {
        bool ok = true;
        int tc[5], tb[5], tt[5];
        for (int l = 0; l < 5 && ok; ++l) {
            int ic, ib, it;
            if (hyp == 0)      { ic = 3*l;   ib = 3*l+1; it = 3*l+2; } // dict order
            else if (hyp == 1) { ic = l;     ib = 5+l;   it = 10+l;  } // arg order
            else               { ib = l;     ic = 5+l;   it = 10+l;  } // sorted keys
            if (in_sizes[ic] != 2*BATCH*HW5[l] ||
                in_sizes[ib] != 4*BATCH*HW5[l] ||
                in_sizes[it] != 1*BATCH*HW5[l]) ok = false;
            tc[l]=ic; tb[l]=ib; tt[l]=it;
        }
        if (ok) { for (int l=0;l<5;++l){mc[l]=tc[l];mb[l]=tb[l];mt[l]=tt[l];} found = true; }
    }
    if (!found) { for (int l=0;l<5;++l){mc[l]=3*l;mb[l]=3*l+1;mt[l]=3*l+2;} }

    P5 C, Bb, T;
    for (int l = 0; l < 5; ++l) {
        C.p[l]  = (const float*)d_in[mc[l]];
        Bb.p[l] = (const float*)d_in[mb[l]];
        T.p[l]  = (const float*)d_in[mt[l]];
    }

    // Workspace layout (6.53 MB total; boxes/scores reuse the wkeys region
    // after k_select has finished reading it — stream-ordered):
    uint8_t* w = (uint8_t*)d_ws;
    float*          wkeys    = (float*)w;                        // 6,285,312 B
    float*          boxes_g  = (float*)w;                        // 1,904,640 B (reuse)
    float*          scores_g = (float*)(w + 2097152);            //   952,320 B (reuse)
    unsigned short* slots_g  = (unsigned short*)(w + 6291456);   //   238,080 B

    k_keys  <<<dim3(1024), dim3(256), 0, stream>>>(C, T, wkeys);
    k_select<<<dim3(160),  dim3(512), 0, stream>>>(wkeys, slots_g);
    k_decode<<<dim3((BATCH*M_TOT + 255)/256), dim3(256), 0, stream>>>(
        C, Bb, T, slots_g, boxes_g, scores_g);
    k_nms   <<<dim3(BATCH), dim3(NTHR_NMS), 0, stream>>>(boxes_g, scores_g, (float*)d_out);
}

// Round 15
// 384.895 us; speedup vs baseline: 37.5142x; 1.3033x over previous
//
#include <hip/hip_runtime.h>
#include <stdint.h>

#define BATCH 32
#define M_TOT 3720          // 1000+1000+1000+576+144
#define NCAND 7440          // M_TOT * 2 classes
#define NPAD 8192
#define SCORE_THR 0.05f
#define IOU_THR 0.6f
#define RCLIP 4.135166556742356f
#define IMG 1536.0f
#define KEYS_PER_B 49104    // 36864+9216+2304+576+144

__device__ __forceinline__ float sigf(float x) {
    return __fdiv_rn(1.0f, __fadd_rn(1.0f, expf(-x)));
}

__device__ __forceinline__ int lvl_of_i(int i, int& loc) {
    if (i < 36864)      { loc = i;         return 0; }
    else if (i < 46080) { loc = i - 36864; return 1; }
    else if (i < 48384) { loc = i - 46080; return 2; }
    else if (i < 48960) { loc = i - 48384; return 3; }
    else                { loc = i - 48960; return 4; }
}

struct P5 { const float* p[5]; };

// ---------- K0: pre-NMS keys, wide (unchanged, green) ----------
__global__ __launch_bounds__(256) void k_keys(P5 CLS, P5 CT, float* __restrict__ wkeys) {
    const int HWs[5] = {36864, 9216, 2304, 576, 144};
    const int total = BATCH * KEYS_PER_B;
    for (int t = blockIdx.x * blockDim.x + threadIdx.x; t < total;
         t += gridDim.x * blockDim.x) {
        int b = t / KEYS_PER_B;
        int i = t - b * KEYS_PER_B;
        int loc; int l = lvl_of_i(i, loc);
        int hw = HWs[l];
        float s0 = sigf(CLS.p[l][(size_t)(2*b)*hw + loc]);
        float s1 = sigf(CLS.p[l][(size_t)(2*b+1)*hw + loc]);
        float sc = sigf(CT.p[l][(size_t)b*hw + loc]);
        wkeys[t] = __fmul_rn(fmaxf(s0, s1), sc);   // > 0 always
    }
}

// ---------- K1: per-(b,l) exact top-k rank order (unchanged, green) --------
__global__ __launch_bounds__(512) void k_select(const float* __restrict__ wkeys,
                                                unsigned short* __restrict__ slots_g) {
    __shared__ unsigned long long cu[2048];   // 16 KB composites
    __shared__ unsigned hist[256];
    __shared__ unsigned sh_bin, sh_krem, sh_cnt;

    const int HWs[5]  = {36864, 9216, 2304, 576, 144};
    const int MOFF[5] = {0, 1000, 2000, 3000, 3576};
    const int KOFF[5] = {0, 36864, 46080, 48384, 48960};

    const int blk = blockIdx.x;        // 0..159
    const int b = blk / 5, l = blk % 5;
    const int tid = threadIdx.x;
    const int hw = HWs[l];
    const int take = (hw < 1000) ? hw : 1000;
    const float* wkey = wkeys + (size_t)b * KEYS_PER_B + KOFF[l];

    int n;
    if (hw > 1000) {
        unsigned pref = 0, krem = 1000;
        for (int p = 0; p < 4; ++p) {
            const int shift = 24 - 8 * p;
            if (tid < 256) hist[tid] = 0;
            __syncthreads();
            for (int i = tid; i < hw; i += 512) {
                unsigned u = __float_as_uint(wkey[i]);
                bool match = (p == 0) || ((u >> (shift + 8)) == pref);
                if (match) atomicAdd(&hist[(u >> shift) & 255u], 1u);
            }
            __syncthreads();
            if (tid == 0) {
                unsigned c = 0; int bsel = 0; unsigned kr = krem;
                for (int bin = 255; bin >= 0; --bin) {
                    unsigned h = hist[bin];
                    if (c + h >= kr) { bsel = bin; kr -= c; break; }
                    c += h;
                }
                sh_bin = (unsigned)bsel;
                sh_krem = kr;
                sh_cnt = 0;
            }
            __syncthreads();
            pref = (pref << 8) | sh_bin;
            krem = sh_krem;
        }
        const unsigned T = pref;
        for (int i = tid; i < hw; i += 512) {
            unsigned u = __float_as_uint(wkey[i]);
            if (u >= T) {
                unsigned pos = atomicAdd(&sh_cnt, 1u);
                if (pos < 2048u)
                    cu[pos] = (((unsigned long long)u) << 20) | (unsigned)(0xFFFFF - i);
            }
        }
        __syncthreads();
        n = (int)sh_cnt; if (n > 2048) n = 2048;
    } else {
        for (int i = tid; i < hw; i += 512) {
            unsigned u = __float_as_uint(wkey[i]);
            cu[i] = (((unsigned long long)u) << 20) | (unsigned)(0xFFFFF - i);
        }
        n = hw;
        __syncthreads();
    }
    for (int a = tid; a < n; a += 512) {
        unsigned long long ka = cu[a];
        int rank = 0;
        for (int q = 0; q < n; ++q) rank += (cu[q] > ka) ? 1 : 0;
        if (rank < take) {
            unsigned loc = 0xFFFFFu - (unsigned)(ka & 0xFFFFFu);
            slots_g[(size_t)b * M_TOT + MOFF[l] + rank] = (unsigned short)loc;
        }
    }
}

// ---------- K2: decode boxes + candidate scores, wide (unchanged, green) ---
__global__ __launch_bounds__(256) void k_decode(P5 CLS, P5 BB, P5 CT,
                                                const unsigned short* __restrict__ slots_g,
                                                float* __restrict__ boxes_g,
                                                float* __restrict__ scores_g) {
    const int HWs[5]  = {36864, 9216, 2304, 576, 144};
    const int Ws[5]   = {192, 96, 48, 24, 12};
    const int STRs[5] = {8, 16, 32, 64, 128};
    int t = blockIdx.x * blockDim.x + threadIdx.x;
    if (t >= BATCH * M_TOT) return;
    int b = t / M_TOT;
    int m = t - b * M_TOT;
    int l;
    if (m < 1000)      l = 0;
    else if (m < 2000) l = 1;
    else if (m < 3000) l = 2;
    else if (m < 3576) l = 3;
    else               l = 4;
    const int hw = HWs[l], w = Ws[l], stride = STRs[l];
    int loc = slots_g[t];

    float ctv = sigf(CT.p[l][(size_t)b*hw + loc]);
    float sc0 = __fmul_rn(sigf(CLS.p[l][(size_t)(2*b+0)*hw + loc]), ctv);
    float sc1 = __fmul_rn(sigf(CLS.p[l][(size_t)(2*b+1)*hw + loc]), ctv);
    scores_g[(size_t)b * NCAND + 2*m + 0] = (sc0 > SCORE_THR) ? sc0 : -1.0f;
    scores_g[(size_t)b * NCAND + 2*m + 1] = (sc1 > SCORE_THR) ? sc1 : -1.0f;

    int yy = loc / w;
    int xx = loc - yy * w;
    const float* bb = BB.p[l];
    float d0 = bb[(size_t)(4*b+0)*hw + loc];
    float d1 = bb[(size_t)(4*b+1)*hw + loc];
    float d2 = bb[(size_t)(4*b+2)*hw + loc];
    float d3 = bb[(size_t)(4*b+3)*hw + loc];
    float a   = (float)(8 * stride);
    float acx = (float)(xx * stride);
    float acy = (float)(yy * stride);
    float dwv = fminf(fmaxf(d2, -RCLIP), RCLIP);
    float dhv = fminf(fmaxf(d3, -RCLIP), RCLIP);
    float pcx = __fadd_rn(acx, __fmul_rn(d0, a));
    float pcy = __fadd_rn(acy, __fmul_rn(d1, a));
    float pw  = __fmul_rn(a, expf(dwv));
    float ph  = __fmul_rn(a, expf(dhv));
    float* bx = boxes_g + (size_t)t * 4;
    bx[0] = fminf(fmaxf(__fsub_rn(pcx, __fmul_rn(0.5f, pw)), 0.0f), IMG);
    bx[1] = fminf(fmaxf(__fsub_rn(pcy, __fmul_rn(0.5f, ph)), 0.0f), IMG);
    bx[2] = fminf(fmaxf(__fadd_rn(pcx, __fmul_rn(0.5f, pw)), 0.0f), IMG);
    bx[3] = fminf(fmaxf(__fadd_rn(pcy, __fmul_rn(0.5f, ph)), 0.0f), IMG);
}

// ---------- K3: NMS = bitonic sort (score desc, idx asc) + 1-wave scan -----
// Exact argmax-NMS semantics including the reference's "sticky box" quirk:
// a picked box with self-IoU <= thr (area <= 0.6e-6) never suppresses itself,
// so jnp.argmax re-picks it for ALL remaining rows. Such boxes are provably
// (fp-exactly, via RN-division monotonicity) never suppressed by others and
// never suppress others, so in scan order: first sticky candidate reached
// fills rows kc..99 and terminates.
__global__ __launch_bounds__(512) void k_nms(const float* __restrict__ boxes_g,
                                             const float* __restrict__ scores_g,
                                             float* __restrict__ out) {
    __shared__ unsigned long long cu[NPAD];   // 64 KB
    const int b = blockIdx.x, tid = threadIdx.x;

    for (int i = tid; i < NPAD; i += 512) {
        if (i < NCAND) {
            float sv = scores_g[(size_t)b * NCAND + i];
            cu[i] = (sv > 0.0f)
                ? ((((unsigned long long)(~__float_as_uint(sv))) << 16) | (unsigned)i)
                : ~0ULL;
        } else {
            cu[i] = ~0ULL;
        }
    }
    __syncthreads();

    // bitonic sort ascending (u64; idx unique -> total order == argmax order)
    for (unsigned kk = 2; kk <= NPAD; kk <<= 1) {
        for (unsigned j = kk >> 1; j > 0; j >>= 1) {
            for (unsigned i = tid; i < NPAD; i += 512) {
                unsigned ixj = i ^ j;
                if (ixj > i) {
                    unsigned long long av = cu[i], bv = cu[ixj];
                    bool up = ((i & kk) == 0);
                    if ((av > bv) == up) { cu[i] = bv; cu[ixj] = av; }
                }
            }
            __syncthreads();
        }
    }

    if (tid >= 64) return;   // wave 0 only from here; no more barriers

    const int lane = tid;
    const float4* bx4 = (const float4*)(boxes_g + (size_t)b * M_TOT * 4);

    float k0x1 = 0, k0y1 = 0, k0x2 = 0, k0y2 = 0, k0a = 0;
    float k1x1 = 0, k1y1 = 0, k1x2 = 0, k1y2 = 0, k1a = 0;
    int kc = 0;
    bool done = false;

    for (int base = 0; base < NPAD && kc < 100 && !done; base += 64) {
        unsigned long long e = cu[base + lane];
        int myvalid = (e != ~0ULL) ? 1 : 0;
        unsigned myidx = (unsigned)(e & 0xFFFFull);
        float mysc = __uint_as_float(~(unsigned)(e >> 16));
        int myc = (int)(myidx & 1u);
        float b0 = 0, b1 = 0, b2 = 0, b3 = 0;
        if (myvalid) {
            float4 v = bx4[myidx >> 1];
            b0 = v.x; b1 = v.y; b2 = v.z; b3 = v.w;
        }
        if (!__any(myvalid)) break;

        for (int j = 0; j < 64 && kc < 100; ++j) {
            if (!__shfl(myvalid, j)) { done = true; break; }   // sorted: rest invalid
            float bx1 = __shfl(b0, j), by1 = __shfl(b1, j);
            float bx2 = __shfl(b2, j), by2 = __shfl(b3, j);
            float score = __shfl(mysc, j);
            int   c     = __shfl(myc, j);

            float offv = c ? (IMG + 1.0f) : 0.0f;
            float ox1 = __fadd_rn(bx1, offv), oy1 = __fadd_rn(by1, offv);
            float ox2 = __fadd_rn(bx2, offv), oy2 = __fadd_rn(by2, offv);
            float ca = __fmul_rn(__fsub_rn(ox2, ox1), __fsub_rn(oy2, oy1));
            bool ov = false;
            if (lane < kc) {
                float ix1 = fmaxf(k0x1, ox1), iy1 = fmaxf(k0y1, oy1);
                float ix2 = fminf(k0x2, ox2), iy2 = fminf(k0y2, oy2);
                float inter = __fmul_rn(fmaxf(__fsub_rn(ix2, ix1), 0.0f),
                                        fmaxf(__fsub_rn(iy2, iy1), 0.0f));
                float uni = fmaxf(__fsub_rn(__fadd_rn(k0a, ca), inter), 1e-6f);
                ov = ov || (__fdiv_rn(inter, uni) > IOU_THR);
            }
            if (lane + 64 < kc) {
                float ix1 = fmaxf(k1x1, ox1), iy1 = fmaxf(k1y1, oy1);
                float ix2 = fminf(k1x2, ox2), iy2 = fminf(k1y2, oy2);
                float inter = __fmul_rn(fmaxf(__fsub_rn(ix2, ix1), 0.0f),
                                        fmaxf(__fsub_rn(iy2, iy1), 0.0f));
                float uni = fmaxf(__fsub_rn(__fadd_rn(k1a, ca), inter), 1e-6f);
                ov = ov || (__fdiv_rn(inter, uni) > IOU_THR);
            }
            if (!__any((int)ov)) {
                // Sticky check: self-IoU = ca / max(2*ca - ca, 1e-6), ref ops.
                float uni_s = fmaxf(__fsub_rn(__fadd_rn(ca, ca), ca), 1e-6f);
                bool sticky = !(__fdiv_rn(ca, uni_s) > IOU_THR);
                if (sticky) {
                    // argmax re-picks this box for every remaining row
                    for (int t2 = kc + lane; t2 < 100; t2 += 64) {
                        float* dr = out + ((size_t)b * 100 + t2) * 5;
                        dr[0] = bx1; dr[1] = by1; dr[2] = bx2; dr[3] = by2; dr[4] = score;
                        out[(size_t)BATCH * 500 + b * 100 + t2] = (float)c;
                    }
                    kc = 100;
                    done = true;
                    break;
                }
                if (lane == 0) {
                    float* dr = out + ((size_t)b * 100 + kc) * 5;
                    dr[0] = bx1; dr[1] = by1; dr[2] = bx2; dr[3] = by2; dr[4] = score;
                    out[(size_t)BATCH * 500 + b * 100 + kc] = (float)c;
                }
                if (kc < 64) {
                    if (lane == kc)      { k0x1 = ox1; k0y1 = oy1; k0x2 = ox2; k0y2 = oy2; k0a = ca; }
                } else {
                    if (lane == kc - 64) { k1x1 = ox1; k1y1 = oy1; k1x2 = ox2; k1y2 = oy2; k1a = ca; }
                }
                ++kc;
            }
        }
    }
    // fill remaining rows (ref writes zeros / -1 when nothing valid remains)
    for (int t2 = kc + lane; t2 < 100; t2 += 64) {
        float* dr = out + ((size_t)b * 100 + t2) * 5;
        dr[0] = 0.0f; dr[1] = 0.0f; dr[2] = 0.0f; dr[3] = 0.0f; dr[4] = 0.0f;
        out[(size_t)BATCH * 500 + b * 100 + t2] = -1.0f;
    }
}

extern "C" void kernel_launch(void* const* d_in, const int* in_sizes, int n_in,
                              void* d_out, int out_size, void* d_ws, size_t ws_size,
                              hipStream_t stream) {
    static const int HW5[5] = {36864, 9216, 2304, 576, 144};
    int mc[5], mb[5], mt[5];
    bool found = false;
    for (int hyp = 0; hyp < 3 && !found; ++hyp) {
        bool ok = true;
        int tc[5], tb[5], tt[5];
        for (int l = 0; l < 5 && ok; ++l) {
            int ic, ib, it;
            if (hyp == 0)      { ic = 3*l;   ib = 3*l+1; it = 3*l+2; } // dict order
            else if (hyp == 1) { ic = l;     ib = 5+l;   it = 10+l;  } // arg order
            else               { ib = l;     ic = 5+l;   it = 10+l;  } // sorted keys
            if (in_sizes[ic] != 2*BATCH*HW5[l] ||
                in_sizes[ib] != 4*BATCH*HW5[l] ||
                in_sizes[it] != 1*BATCH*HW5[l]) ok = false;
            tc[l]=ic; tb[l]=ib; tt[l]=it;
        }
        if (ok) { for (int l=0;l<5;++l){mc[l]=tc[l];mb[l]=tb[l];mt[l]=tt[l];} found = true; }
    }
    if (!found) { for (int l=0;l<5;++l){mc[l]=3*l;mb[l]=3*l+1;mt[l]=3*l+2;} }

    P5 C, Bb, T;
    for (int l = 0; l < 5; ++l) {
        C.p[l]  = (const float*)d_in[mc[l]];
        Bb.p[l] = (const float*)d_in[mb[l]];
        T.p[l]  = (const float*)d_in[mt[l]];
    }

    // Workspace layout (6.53 MB; boxes/scores reuse wkeys region after
    // k_select has finished reading it — stream-ordered):
    uint8_t* w = (uint8_t*)d_ws;
    float*          wkeys    = (float*)w;                        // 6,285,312 B
    float*          boxes_g  = (float*)w;                        // 1,904,640 B (reuse)
    float*          scores_g = (float*)(w + 2097152);            //   952,320 B (reuse)
    unsigned short* slots_g  = (unsigned short*)(w + 6291456);   //   238,080 B

    k_keys  <<<dim3(1024), dim3(256), 0, stream>>>(C, T, wkeys);
    k_select<<<dim3(160),  dim3(512), 0, stream>>>(wkeys, slots_g);
    k_decode<<<dim3((BATCH*M_TOT + 255)/256), dim3(256), 0, stream>>>(
        C, Bb, T, slots_g, boxes_g, scores_g);
    k_nms   <<<dim3(BATCH), dim3(512), 0, stream>>>(boxes_g, scores_g, (float*)d_out);
}

// Round 16
// 322.440 us; speedup vs baseline: 44.7804x; 1.1937x over previous
//
#include <hip/hip_runtime.h>
#include <stdint.h>

#define BATCH 32
#define M_TOT 3720          // 1000+1000+1000+576+144
#define NCAND 7440          // M_TOT * 2 classes
#define NPAD 8192
#define SCORE_THR 0.05f
#define IOU_THR 0.6f
#define RCLIP 4.135166556742356f
#define IMG 1536.0f
#define KEYS_PER_B 49104    // 36864+9216+2304+576+144

__device__ __forceinline__ float sigf(float x) {
    return __fdiv_rn(1.0f, __fadd_rn(1.0f, expf(-x)));
}

__device__ __forceinline__ int lvl_of_i(int i, int& loc) {
    if (i < 36864)      { loc = i;         return 0; }
    else if (i < 46080) { loc = i - 36864; return 1; }
    else if (i < 48384) { loc = i - 46080; return 2; }
    else if (i < 48960) { loc = i - 48384; return 3; }
    else                { loc = i - 48960; return 4; }
}

struct P5 { const float* p[5]; };

// ---------- K0: pre-NMS keys, wide (unchanged, green) ----------
__global__ __launch_bounds__(256) void k_keys(P5 CLS, P5 CT, float* __restrict__ wkeys) {
    const int HWs[5] = {36864, 9216, 2304, 576, 144};
    const int total = BATCH * KEYS_PER_B;
    for (int t = blockIdx.x * blockDim.x + threadIdx.x; t < total;
         t += gridDim.x * blockDim.x) {
        int b = t / KEYS_PER_B;
        int i = t - b * KEYS_PER_B;
        int loc; int l = lvl_of_i(i, loc);
        int hw = HWs[l];
        float s0 = sigf(CLS.p[l][(size_t)(2*b)*hw + loc]);
        float s1 = sigf(CLS.p[l][(size_t)(2*b+1)*hw + loc]);
        float sc = sigf(CT.p[l][(size_t)b*hw + loc]);
        wkeys[t] = __fmul_rn(fmaxf(s0, s1), sc);   // > 0 always
    }
}

// ---------- K1: per-(b,l) exact top-k rank order (unchanged, green) --------
__global__ __launch_bounds__(512) void k_select(const float* __restrict__ wkeys,
                                                unsigned short* __restrict__ slots_g) {
    __shared__ unsigned long long cu[2048];   // 16 KB composites
    __shared__ unsigned hist[256];
    __shared__ unsigned sh_bin, sh_krem, sh_cnt;

    const int HWs[5]  = {36864, 9216, 2304, 576, 144};
    const int MOFF[5] = {0, 1000, 2000, 3000, 3576};
    const int KOFF[5] = {0, 36864, 46080, 48384, 48960};

    const int blk = blockIdx.x;        // 0..159
    const int b = blk / 5, l = blk % 5;
    const int tid = threadIdx.x;
    const int hw = HWs[l];
    const int take = (hw < 1000) ? hw : 1000;
    const float* wkey = wkeys + (size_t)b * KEYS_PER_B + KOFF[l];

    int n;
    if (hw > 1000) {
        unsigned pref = 0, krem = 1000;
        for (int p = 0; p < 4; ++p) {
            const int shift = 24 - 8 * p;
            if (tid < 256) hist[tid] = 0;
            __syncthreads();
            for (int i = tid; i < hw; i += 512) {
                unsigned u = __float_as_uint(wkey[i]);
                bool match = (p == 0) || ((u >> (shift + 8)) == pref);
                if (match) atomicAdd(&hist[(u >> shift) & 255u], 1u);
            }
            __syncthreads();
            if (tid == 0) {
                unsigned c = 0; int bsel = 0; unsigned kr = krem;
                for (int bin = 255; bin >= 0; --bin) {
                    unsigned h = hist[bin];
                    if (c + h >= kr) { bsel = bin; kr -= c; break; }
                    c += h;
                }
                sh_bin = (unsigned)bsel;
                sh_krem = kr;
                sh_cnt = 0;
            }
            __syncthreads();
            pref = (pref << 8) | sh_bin;
            krem = sh_krem;
        }
        const unsigned T = pref;
        for (int i = tid; i < hw; i += 512) {
            unsigned u = __float_as_uint(wkey[i]);
            if (u >= T) {
                unsigned pos = atomicAdd(&sh_cnt, 1u);
                if (pos < 2048u)
                    cu[pos] = (((unsigned long long)u) << 20) | (unsigned)(0xFFFFF - i);
            }
        }
        __syncthreads();
        n = (int)sh_cnt; if (n > 2048) n = 2048;
    } else {
        for (int i = tid; i < hw; i += 512) {
            unsigned u = __float_as_uint(wkey[i]);
            cu[i] = (((unsigned long long)u) << 20) | (unsigned)(0xFFFFF - i);
        }
        n = hw;
        __syncthreads();
    }
    for (int a = tid; a < n; a += 512) {
        unsigned long long ka = cu[a];
        int rank = 0;
        for (int q = 0; q < n; ++q) rank += (cu[q] > ka) ? 1 : 0;
        if (rank < take) {
            unsigned loc = 0xFFFFFu - (unsigned)(ka & 0xFFFFFu);
            slots_g[(size_t)b * M_TOT + MOFF[l] + rank] = (unsigned short)loc;
        }
    }
}

// ---------- K2: decode boxes + candidate scores, wide (unchanged, green) ---
__global__ __launch_bounds__(256) void k_decode(P5 CLS, P5 BB, P5 CT,
                                                const unsigned short* __restrict__ slots_g,
                                                float* __restrict__ boxes_g,
                                                float* __restrict__ scores_g) {
    const int HWs[5]  = {36864, 9216, 2304, 576, 144};
    const int Ws[5]   = {192, 96, 48, 24, 12};
    const int STRs[5] = {8, 16, 32, 64, 128};
    int t = blockIdx.x * blockDim.x + threadIdx.x;
    if (t >= BATCH * M_TOT) return;
    int b = t / M_TOT;
    int m = t - b * M_TOT;
    int l;
    if (m < 1000)      l = 0;
    else if (m < 2000) l = 1;
    else if (m < 3000) l = 2;
    else if (m < 3576) l = 3;
    else               l = 4;
    const int hw = HWs[l], w = Ws[l], stride = STRs[l];
    int loc = slots_g[t];

    float ctv = sigf(CT.p[l][(size_t)b*hw + loc]);
    float sc0 = __fmul_rn(sigf(CLS.p[l][(size_t)(2*b+0)*hw + loc]), ctv);
    float sc1 = __fmul_rn(sigf(CLS.p[l][(size_t)(2*b+1)*hw + loc]), ctv);
    scores_g[(size_t)b * NCAND + 2*m + 0] = (sc0 > SCORE_THR) ? sc0 : -1.0f;
    scores_g[(size_t)b * NCAND + 2*m + 1] = (sc1 > SCORE_THR) ? sc1 : -1.0f;

    int yy = loc / w;
    int xx = loc - yy * w;
    const float* bb = BB.p[l];
    float d0 = bb[(size_t)(4*b+0)*hw + loc];
    float d1 = bb[(size_t)(4*b+1)*hw + loc];
    float d2 = bb[(size_t)(4*b+2)*hw + loc];
    float d3 = bb[(size_t)(4*b+3)*hw + loc];
    float a   = (float)(8 * stride);
    float acx = (float)(xx * stride);
    float acy = (float)(yy * stride);
    float dwv = fminf(fmaxf(d2, -RCLIP), RCLIP);
    float dhv = fminf(fmaxf(d3, -RCLIP), RCLIP);
    float pcx = __fadd_rn(acx, __fmul_rn(d0, a));
    float pcy = __fadd_rn(acy, __fmul_rn(d1, a));
    float pw  = __fmul_rn(a, expf(dwv));
    float ph  = __fmul_rn(a, expf(dhv));
    float* bx = boxes_g + (size_t)t * 4;
    bx[0] = fminf(fmaxf(__fsub_rn(pcx, __fmul_rn(0.5f, pw)), 0.0f), IMG);
    bx[1] = fminf(fmaxf(__fsub_rn(pcy, __fmul_rn(0.5f, ph)), 0.0f), IMG);
    bx[2] = fminf(fmaxf(__fadd_rn(pcx, __fmul_rn(0.5f, pw)), 0.0f), IMG);
    bx[3] = fminf(fmaxf(__fadd_rn(pcy, __fmul_rn(0.5f, ph)), 0.0f), IMG);
}

// ---------- K3: NMS = bitonic sort + candidate-parallel chunked scan -------
// Same exact semantics as the green round-15 scan (incl. sticky-box rule),
// restructured: lanes own candidates (64/chunk); kept-set check runs
// candidate-parallel against LDS-kept boxes; serial work only per PICK.
__global__ __launch_bounds__(1024) void k_nms(const float* __restrict__ boxes_g,
                                              const float* __restrict__ scores_g,
                                              float* __restrict__ out) {
    __shared__ unsigned long long cu[NPAD];   // 64 KB
    const int b = blockIdx.x, tid = threadIdx.x;

    for (int i = tid; i < NPAD; i += 1024) {
        if (i < NCAND) {
            float sv = scores_g[(size_t)b * NCAND + i];
            cu[i] = (sv > 0.0f)
                ? ((((unsigned long long)(~__float_as_uint(sv))) << 16) | (unsigned)i)
                : ~0ULL;
        } else {
            cu[i] = ~0ULL;
        }
    }
    __syncthreads();

    // bitonic sort ascending (u64; idx unique -> total order == argmax order)
    for (unsigned kk = 2; kk <= NPAD; kk <<= 1) {
        for (unsigned j = kk >> 1; j > 0; j >>= 1) {
            for (unsigned i = tid; i < NPAD; i += 1024) {
                unsigned ixj = i ^ j;
                if (ixj > i) {
                    unsigned long long av = cu[i], bv = cu[ixj];
                    bool up = ((i & kk) == 0);
                    if ((av > bv) == up) { cu[i] = bv; cu[ixj] = av; }
                }
            }
            __syncthreads();
        }
    }

    if (tid >= 64) return;   // wave 0 only; no more barriers

    const int lane = tid;
    const float4* bx4 = (const float4*)(boxes_g + (size_t)b * M_TOT * 4);
    // kept-box scratch reuses cu tail: positions >= NCAND are always padding
    // after the sort (752 u64 = 6016 B >= 100*5*4 B), and the scan never
    // reads cu[base+lane] with base+lane >= NCAND (guarded below).
    float* keptL = (float*)(cu + NCAND);

    int kc = 0;
    bool done = false;

    for (int base = 0; base < NCAND && kc < 100 && !done; base += 64) {
        unsigned long long e = (base + lane < NCAND) ? cu[base + lane] : ~0ULL;
        bool valid = (e != ~0ULL);
        unsigned myidx = (unsigned)(e & 0xFFFFull);
        float myscore = __uint_as_float(~(unsigned)(e >> 16));
        int myc = (int)(myidx & 1u);
        float bx1 = 0, by1 = 0, bx2 = 0, by2 = 0;
        if (valid) {
            float4 v = bx4[myidx >> 1];
            bx1 = v.x; by1 = v.y; bx2 = v.z; by2 = v.w;
        }
        float offv = myc ? (IMG + 1.0f) : 0.0f;
        float ox1 = __fadd_rn(bx1, offv), oy1 = __fadd_rn(by1, offv);
        float ox2 = __fadd_rn(bx2, offv), oy2 = __fadd_rn(by2, offv);
        float ca = __fmul_rn(__fsub_rn(ox2, ox1), __fsub_rn(oy2, oy1));
        // sticky: self-IoU = ca / max(2*ca - ca, 1e-6), ref op sequence
        float uni_s = fmaxf(__fsub_rn(__fadd_rn(ca, ca), ca), 1e-6f);
        bool mySticky = !(__fdiv_rn(ca, uni_s) > IOU_THR);

        const bool hasInvalid = (__ballot(!valid) != 0ULL);

        // candidate-parallel check vs kept set at chunk start
        bool ov = false;
        if (valid) {
            for (int k = 0; k < kc && !ov; ++k) {
                float px1 = keptL[k*5+0], py1 = keptL[k*5+1];
                float px2 = keptL[k*5+2], py2 = keptL[k*5+3];
                float pa  = keptL[k*5+4];
                float ix1 = fmaxf(px1, ox1), iy1 = fmaxf(py1, oy1);
                float ix2 = fminf(px2, ox2), iy2 = fminf(py2, oy2);
                float inter = __fmul_rn(fmaxf(__fsub_rn(ix2, ix1), 0.0f),
                                        fmaxf(__fsub_rn(iy2, iy1), 0.0f));
                float uni = fmaxf(__fsub_rn(__fadd_rn(pa, ca), inter), 1e-6f);
                ov = (__fdiv_rn(inter, uni) > IOU_THR);
            }
        }
        bool myAlive = valid && !ov;
        unsigned long long aliveMask = __ballot(myAlive);

        // serial only over PICKS within the chunk (lowest lane first = sorted order)
        while (aliveMask != 0ULL && kc < 100) {
            int j = __ffsll(aliveMask) - 1;
            float pbx1 = __shfl(bx1, j), pby1 = __shfl(by1, j);
            float pbx2 = __shfl(bx2, j), pby2 = __shfl(by2, j);
            float pox1 = __shfl(ox1, j), poy1 = __shfl(oy1, j);
            float pox2 = __shfl(ox2, j), poy2 = __shfl(oy2, j);
            float pca  = __shfl(ca, j);
            float psc  = __shfl(myscore, j);
            int   pc   = __shfl(myc, j);
            int   pst  = __shfl((int)mySticky, j);

            if (pst) {
                // argmax re-picks this box for every remaining row
                for (int t2 = kc + lane; t2 < 100; t2 += 64) {
                    float* dr = out + ((size_t)b * 100 + t2) * 5;
                    dr[0] = pbx1; dr[1] = pby1; dr[2] = pbx2; dr[3] = pby2; dr[4] = psc;
                    out[(size_t)BATCH * 500 + b * 100 + t2] = (float)pc;
                }
                kc = 100;
                done = true;
                break;
            }
            if (lane == 0) {
                float* dr = out + ((size_t)b * 100 + kc) * 5;
                dr[0] = pbx1; dr[1] = pby1; dr[2] = pbx2; dr[3] = pby2; dr[4] = psc;
                out[(size_t)BATCH * 500 + b * 100 + kc] = (float)pc;
                keptL[kc*5+0] = pox1; keptL[kc*5+1] = poy1;
                keptL[kc*5+2] = pox2; keptL[kc*5+3] = poy2;
                keptL[kc*5+4] = pca;
            }
            ++kc;
            // suppress remaining alive candidates in this chunk vs the pick
            if (myAlive && lane > j) {
                float ix1 = fmaxf(pox1, ox1), iy1 = fmaxf(poy1, oy1);
                float ix2 = fminf(pox2, ox2), iy2 = fminf(poy2, oy2);
                float inter = __fmul_rn(fmaxf(__fsub_rn(ix2, ix1), 0.0f),
                                        fmaxf(__fsub_rn(iy2, iy1), 0.0f));
                float uni = fmaxf(__fsub_rn(__fadd_rn(pca, ca), inter), 1e-6f);
                if (__fdiv_rn(inter, uni) > IOU_THR) myAlive = false;
            }
            if (lane == j) myAlive = false;
            aliveMask = __ballot(myAlive);
        }
        if (hasInvalid) break;   // sorted: everything after this chunk invalid
    }
    // fill remaining rows (ref writes zeros / -1 when nothing valid remains)
    for (int t2 = kc + lane; t2 < 100; t2 += 64) {
        float* dr = out + ((size_t)b * 100 + t2) * 5;
        dr[0] = 0.0f; dr[1] = 0.0f; dr[2] = 0.0f; dr[3] = 0.0f; dr[4] = 0.0f;
        out[(size_t)BATCH * 500 + b * 100 + t2] = -1.0f;
    }
}

extern "C" void kernel_launch(void* const* d_in, const int* in_sizes, int n_in,
                              void* d_out, int out_size, void* d_ws, size_t ws_size,
                              hipStream_t stream) {
    static const int HW5[5] = {36864, 9216, 2304, 576, 144};
    int mc[5], mb[5], mt[5];
    bool found = false;
    for (int hyp = 0; hyp < 3 && !found; ++hyp) {
        bool ok = true;
        int tc[5], tb[5], tt[5];
        for (int l = 0; l < 5 && ok; ++l) {
            int ic, ib, it;
            if (hyp == 0)      { ic = 3*l;   ib = 3*l+1; it = 3*l+2; } // dict order
            else if (hyp == 1) { ic = l;     ib = 5+l;   it = 10+l;  } // arg order
            else               { ib = l;     ic = 5+l;   it = 10+l;  } // sorted keys
            if (in_sizes[ic] != 2*BATCH*HW5[l] ||
                in_sizes[ib] != 4*BATCH*HW5[l] ||
                in_sizes[it] != 1*BATCH*HW5[l]) ok = false;
            tc[l]=ic; tb[l]=ib; tt[l]=it;
        }
        if (ok) { for (int l=0;l<5;++l){mc[l]=tc[l];mb[l]=tb[l];mt[l]=tt[l];} found = true; }
    }
    if (!found) { for (int l=0;l<5;++l){mc[l]=3*l;mb[l]=3*l+1;mt[l]=3*l+2;} }

    P5 C, Bb, T;
    for (int l = 0; l < 5; ++l) {
        C.p[l]  = (const float*)d_in[mc[l]];
        Bb.p[l] = (const float*)d_in[mb[l]];
        T.p[l]  = (const float*)d_in[mt[l]];
    }

    // Workspace layout (6.53 MB; boxes/scores reuse wkeys region after
    // k_select has finished reading it — stream-ordered):
    uint8_t* w = (uint8_t*)d_ws;
    float*          wkeys    = (float*)w;                        // 6,285,312 B
    float*          boxes_g  = (float*)w;                        // 1,904,640 B (reuse)
    float*          scores_g = (float*)(w + 2097152);            //   952,320 B (reuse)
    unsigned short* slots_g  = (unsigned short*)(w + 6291456);   //   238,080 B

    k_keys  <<<dim3(1024), dim3(256), 0, stream>>>(C, T, wkeys);
    k_select<<<dim3(160),  dim3(512), 0, stream>>>(wkeys, slots_g);
    k_decode<<<dim3((BATCH*M_TOT + 255)/256), dim3(256), 0, stream>>>(
        C, Bb, T, slots_g, boxes_g, scores_g);
    k_nms   <<<dim3(BATCH), dim3(1024), 0, stream>>>(boxes_g, scores_g, (float*)d_out);
}

// Round 17
// 314.372 us; speedup vs baseline: 45.9298x; 1.0257x over previous
//
#include <hip/hip_runtime.h>
#include <stdint.h>

#define BATCH 32
#define M_TOT 3720          // 1000+1000+1000+576+144
#define NCAND 7440          // M_TOT * 2 classes
#define NPAD 8192
#define SCORE_THR 0.05f
#define IOU_THR 0.6f
#define RCLIP 4.135166556742356f
#define IMG 1536.0f
#define KEYS_PER_B 49104    // 36864+9216+2304+576+144

__device__ __forceinline__ float sigf(float x) {
    return __fdiv_rn(1.0f, __fadd_rn(1.0f, expf(-x)));
}

struct P5 { const float* p[5]; };

// ---------- K1: fused keys + per-(b,l) exact top-k rank order --------------
// Pass 0 computes the pre-NMS key from inputs (bit-identical math to the old
// k_keys), writes it to wkeys, and histograms its top byte in one sweep.
__global__ __launch_bounds__(512) void k_select(P5 CLS, P5 CT,
                                                float* __restrict__ wkeys,
                                                unsigned short* __restrict__ slots_g) {
    __shared__ unsigned long long cu[2048];   // 16 KB composites
    __shared__ unsigned hist[256];
    __shared__ unsigned sh_bin, sh_krem, sh_cnt;

    const int HWs[5]  = {36864, 9216, 2304, 576, 144};
    const int MOFF[5] = {0, 1000, 2000, 3000, 3576};
    const int KOFF[5] = {0, 36864, 46080, 48384, 48960};

    const int blk = blockIdx.x;        // 0..159
    const int b = blk / 5, l = blk % 5;
    const int tid = threadIdx.x;
    const int hw = HWs[l];
    const int take = (hw < 1000) ? hw : 1000;
    const float* cls = CLS.p[l];
    const float* ctr = CT.p[l];
    float* wkey = wkeys + (size_t)b * KEYS_PER_B + KOFF[l];

    int n;
    if (hw > 1000) {
        unsigned pref = 0, krem = 1000;
        for (int p = 0; p < 4; ++p) {
            const int shift = 24 - 8 * p;
            if (tid < 256) hist[tid] = 0;
            __syncthreads();
            if (p == 0) {
                for (int i = tid; i < hw; i += 512) {
                    float s0 = sigf(cls[(size_t)(2*b)*hw + i]);
                    float s1 = sigf(cls[(size_t)(2*b+1)*hw + i]);
                    float sc = sigf(ctr[(size_t)b*hw + i]);
                    float kv = __fmul_rn(fmaxf(s0, s1), sc);   // > 0 always
                    wkey[i] = kv;
                    atomicAdd(&hist[(__float_as_uint(kv) >> 24) & 255u], 1u);
                }
            } else {
                for (int i = tid; i < hw; i += 512) {
                    unsigned u = __float_as_uint(wkey[i]);
                    if ((u >> (shift + 8)) == pref)
                        atomicAdd(&hist[(u >> shift) & 255u], 1u);
                }
            }
            __syncthreads();
            if (tid == 0) {
                unsigned c = 0; int bsel = 0; unsigned kr = krem;
                for (int bin = 255; bin >= 0; --bin) {
                    unsigned h = hist[bin];
                    if (c + h >= kr) { bsel = bin; kr -= c; break; }
                    c += h;
                }
                sh_bin = (unsigned)bsel;
                sh_krem = kr;
                sh_cnt = 0;
            }
            __syncthreads();
            pref = (pref << 8) | sh_bin;
            krem = sh_krem;
        }
        const unsigned T = pref;
        for (int i = tid; i < hw; i += 512) {
            unsigned u = __float_as_uint(wkey[i]);
            if (u >= T) {
                unsigned pos = atomicAdd(&sh_cnt, 1u);
                if (pos < 2048u)
                    cu[pos] = (((unsigned long long)u) << 20) | (unsigned)(0xFFFFF - i);
            }
        }
        __syncthreads();
        n = (int)sh_cnt; if (n > 2048) n = 2048;
    } else {
        // small levels: composites straight from inputs (identical key bits)
        for (int i = tid; i < hw; i += 512) {
            float s0 = sigf(cls[(size_t)(2*b)*hw + i]);
            float s1 = sigf(cls[(size_t)(2*b+1)*hw + i]);
            float sc = sigf(ctr[(size_t)b*hw + i]);
            unsigned u = __float_as_uint(__fmul_rn(fmaxf(s0, s1), sc));
            cu[i] = (((unsigned long long)u) << 20) | (unsigned)(0xFFFFF - i);
        }
        n = hw;
        __syncthreads();
    }
    // rank-by-count (composite order == value desc, loc asc; entries unique)
    for (int a = tid; a < n; a += 512) {
        unsigned long long ka = cu[a];
        int rank = 0;
        for (int q = 0; q < n; ++q) rank += (cu[q] > ka) ? 1 : 0;
        if (rank < take) {
            unsigned loc = 0xFFFFFu - (unsigned)(ka & 0xFFFFFu);
            slots_g[(size_t)b * M_TOT + MOFF[l] + rank] = (unsigned short)loc;
        }
    }
}

// ---------- K2: decode boxes + candidate scores, wide (unchanged, green) ---
__global__ __launch_bounds__(256) void k_decode(P5 CLS, P5 BB, P5 CT,
                                                const unsigned short* __restrict__ slots_g,
                                                float* __restrict__ boxes_g,
                                                float* __restrict__ scores_g) {
    const int HWs[5]  = {36864, 9216, 2304, 576, 144};
    const int Ws[5]   = {192, 96, 48, 24, 12};
    const int STRs[5] = {8, 16, 32, 64, 128};
    int t = blockIdx.x * blockDim.x + threadIdx.x;
    if (t >= BATCH * M_TOT) return;
    int b = t / M_TOT;
    int m = t - b * M_TOT;
    int l;
    if (m < 1000)      l = 0;
    else if (m < 2000) l = 1;
    else if (m < 3000) l = 2;
    else if (m < 3576) l = 3;
    else               l = 4;
    const int hw = HWs[l], w = Ws[l], stride = STRs[l];
    int loc = slots_g[t];

    float ctv = sigf(CT.p[l][(size_t)b*hw + loc]);
    float sc0 = __fmul_rn(sigf(CLS.p[l][(size_t)(2*b+0)*hw + loc]), ctv);
    float sc1 = __fmul_rn(sigf(CLS.p[l][(size_t)(2*b+1)*hw + loc]), ctv);
    scores_g[(size_t)b * NCAND + 2*m + 0] = (sc0 > SCORE_THR) ? sc0 : -1.0f;
    scores_g[(size_t)b * NCAND + 2*m + 1] = (sc1 > SCORE_THR) ? sc1 : -1.0f;

    int yy = loc / w;
    int xx = loc - yy * w;
    const float* bb = BB.p[l];
    float d0 = bb[(size_t)(4*b+0)*hw + loc];
    float d1 = bb[(size_t)(4*b+1)*hw + loc];
    float d2 = bb[(size_t)(4*b+2)*hw + loc];
    float d3 = bb[(size_t)(4*b+3)*hw + loc];
    float a   = (float)(8 * stride);
    float acx = (float)(xx * stride);
    float acy = (float)(yy * stride);
    float dwv = fminf(fmaxf(d2, -RCLIP), RCLIP);
    float dhv = fminf(fmaxf(d3, -RCLIP), RCLIP);
    float pcx = __fadd_rn(acx, __fmul_rn(d0, a));
    float pcy = __fadd_rn(acy, __fmul_rn(d1, a));
    float pw  = __fmul_rn(a, expf(dwv));
    float ph  = __fmul_rn(a, expf(dhv));
    float* bx = boxes_g + (size_t)t * 4;
    bx[0] = fminf(fmaxf(__fsub_rn(pcx, __fmul_rn(0.5f, pw)), 0.0f), IMG);
    bx[1] = fminf(fmaxf(__fsub_rn(pcy, __fmul_rn(0.5f, ph)), 0.0f), IMG);
    bx[2] = fminf(fmaxf(__fadd_rn(pcx, __fmul_rn(0.5f, pw)), 0.0f), IMG);
    bx[3] = fminf(fmaxf(__fadd_rn(pcy, __fmul_rn(0.5f, ph)), 0.0f), IMG);
}

// ---------- K3: NMS = register-bitonic sort + candidate-parallel scan ------
// Same comparator and network as the green LDS bitonic (u64 >, up=!(i&k),
// lower-keeps-min iff up). Element i lives in thread i/8, reg i%8:
//   j<8      -> in-register swap
//   8<=j<512 -> __shfl_xor with mask j/8 (wave-local, no barrier)
//   j>=512   -> LDS exchange (2 barriers); only 10 such passes.
// Scan identical to green round 16 (incl. sticky-box rule).
__global__ __launch_bounds__(1024) void k_nms(const float* __restrict__ boxes_g,
                                              const float* __restrict__ scores_g,
                                              float* __restrict__ out) {
    __shared__ unsigned long long cu[NPAD];   // 64 KB
    const int b = blockIdx.x, tid = threadIdx.x;

    // load 8 elements/thread (NCAND = 930*8 exactly -> clean valid/pad split)
    unsigned long long v[8];
    if (tid < 930) {
        const float4* s4 = (const float4*)(scores_g + (size_t)b * NCAND) + tid * 2;
        float4 a4 = s4[0], c4 = s4[1];
        float ss[8] = {a4.x, a4.y, a4.z, a4.w, c4.x, c4.y, c4.z, c4.w};
#pragma unroll
        for (int r = 0; r < 8; ++r) {
            int i = tid * 8 + r;
            v[r] = (ss[r] > 0.0f)
                ? ((((unsigned long long)(~__float_as_uint(ss[r]))) << 16) | (unsigned)i)
                : ~0ULL;
        }
    } else {
#pragma unroll
        for (int r = 0; r < 8; ++r) v[r] = ~0ULL;
    }

    for (unsigned kk = 2; kk <= NPAD; kk <<= 1) {
        for (unsigned j = kk >> 1; j > 0; j >>= 1) {
            if (j >= 512) {
                __syncthreads();
#pragma unroll
                for (int r = 0; r < 8; ++r) cu[tid * 8 + r] = v[r];
                __syncthreads();
#pragma unroll
                for (int r = 0; r < 8; ++r) {
                    unsigned i = tid * 8 + r;
                    unsigned long long pv = cu[i ^ j];
                    bool up = ((i & kk) == 0);
                    bool lower = ((i & j) == 0);
                    bool keepmin = (lower == up);
                    v[r] = keepmin ? (v[r] < pv ? v[r] : pv)
                                   : (v[r] > pv ? v[r] : pv);
                }
            } else if (j >= 8) {
                unsigned m = j >> 3;
#pragma unroll
                for (int r = 0; r < 8; ++r) {
                    unsigned long long pv = __shfl_xor(v[r], (int)m, 64);
                    unsigned i = tid * 8 + r;
                    bool up = ((i & kk) == 0);
                    bool lower = ((i & j) == 0);
                    bool keepmin = (lower == up);
                    v[r] = keepmin ? (v[r] < pv ? v[r] : pv)
                                   : (v[r] > pv ? v[r] : pv);
                }
            } else {
#pragma unroll
                for (int r = 0; r < 8; ++r) {
                    if ((r & j) == 0) {
                        unsigned i = tid * 8 + r;
                        bool up = ((i & kk) == 0);
                        unsigned long long a = v[r], b2 = v[r | j];
                        if ((a > b2) == up) { v[r] = b2; v[r | j] = a; }
                    }
                }
            }
        }
    }
    __syncthreads();
#pragma unroll
    for (int r = 0; r < 8; ++r) cu[tid * 8 + r] = v[r];
    __syncthreads();

    if (tid >= 64) return;   // wave 0 only; no more barriers

    const int lane = tid;
    const float4* bx4 = (const float4*)(boxes_g + (size_t)b * M_TOT * 4);
    // kept-box scratch reuses cu tail: positions >= NCAND are always pads
    // after the sort; scan never reads cu beyond NCAND (guarded below).
    float* keptL = (float*)(cu + NCAND);

    int kc = 0;
    bool done = false;

    for (int base = 0; base < NCAND && kc < 100 && !done; base += 64) {
        unsigned long long e = (base + lane < NCAND) ? cu[base + lane] : ~0ULL;
        bool valid = (e != ~0ULL);
        unsigned myidx = (unsigned)(e & 0xFFFFull);
        float myscore = __uint_as_float(~(unsigned)(e >> 16));
        int myc = (int)(myidx & 1u);
        float bx1 = 0, by1 = 0, bx2 = 0, by2 = 0;
        if (valid) {
            float4 vv = bx4[myidx >> 1];
            bx1 = vv.x; by1 = vv.y; bx2 = vv.z; by2 = vv.w;
        }
        float offv = myc ? (IMG + 1.0f) : 0.0f;
        float ox1 = __fadd_rn(bx1, offv), oy1 = __fadd_rn(by1, offv);
        float ox2 = __fadd_rn(bx2, offv), oy2 = __fadd_rn(by2, offv);
        float ca = __fmul_rn(__fsub_rn(ox2, ox1), __fsub_rn(oy2, oy1));
        // sticky: self-IoU = ca / max(2*ca - ca, 1e-6), ref op sequence
        float uni_s = fmaxf(__fsub_rn(__fadd_rn(ca, ca), ca), 1e-6f);
        bool mySticky = !(__fdiv_rn(ca, uni_s) > IOU_THR);

        const bool hasInvalid = (__ballot(!valid) != 0ULL);

        // candidate-parallel check vs kept set at chunk start
        bool ov = false;
        if (valid) {
            for (int k = 0; k < kc && !ov; ++k) {
                float px1 = keptL[k*5+0], py1 = keptL[k*5+1];
                float px2 = keptL[k*5+2], py2 = keptL[k*5+3];
                float pa  = keptL[k*5+4];
                float ix1 = fmaxf(px1, ox1), iy1 = fmaxf(py1, oy1);
                float ix2 = fminf(px2, ox2), iy2 = fminf(py2, oy2);
                float inter = __fmul_rn(fmaxf(__fsub_rn(ix2, ix1), 0.0f),
                                        fmaxf(__fsub_rn(iy2, iy1), 0.0f));
                float uni = fmaxf(__fsub_rn(__fadd_rn(pa, ca), inter), 1e-6f);
                ov = (__fdiv_rn(inter, uni) > IOU_THR);
            }
        }
        bool myAlive = valid && !ov;
        unsigned long long aliveMask = __ballot(myAlive);

        // serial only over PICKS within the chunk (lowest lane = sorted order)
        while (aliveMask != 0ULL && kc < 100) {
            int j = __ffsll(aliveMask) - 1;
            float pbx1 = __shfl(bx1, j), pby1 = __shfl(by1, j);
            float pbx2 = __shfl(bx2, j), pby2 = __shfl(by2, j);
            float pox1 = __shfl(ox1, j), poy1 = __shfl(oy1, j);
            float pox2 = __shfl(ox2, j), poy2 = __shfl(oy2, j);
            float pca  = __shfl(ca, j);
            float psc  = __shfl(myscore, j);
            int   pc   = __shfl(myc, j);
            int   pst  = __shfl((int)mySticky, j);

            if (pst) {
                for (int t2 = kc + lane; t2 < 100; t2 += 64) {
                    float* dr = out + ((size_t)b * 100 + t2) * 5;
                    dr[0] = pbx1; dr[1] = pby1; dr[2] = pbx2; dr[3] = pby2; dr[4] = psc;
                    out[(size_t)BATCH * 500 + b * 100 + t2] = (float)pc;
                }
                kc = 100;
                done = true;
                break;
            }
            if (lane == 0) {
                float* dr = out + ((size_t)b * 100 + kc) * 5;
                dr[0] = pbx1; dr[1] = pby1; dr[2] = pbx2; dr[3] = pby2; dr[4] = psc;
                out[(size_t)BATCH * 500 + b * 100 + kc] = (float)pc;
                keptL[kc*5+0] = pox1; keptL[kc*5+1] = poy1;
                keptL[kc*5+2] = pox2; keptL[kc*5+3] = poy2;
                keptL[kc*5+4] = pca;
            }
            ++kc;
            if (myAlive && lane > j) {
                float ix1 = fmaxf(pox1, ox1), iy1 = fmaxf(poy1, oy1);
                float ix2 = fminf(pox2, ox2), iy2 = fminf(poy2, oy2);
                float inter = __fmul_rn(fmaxf(__fsub_rn(ix2, ix1), 0.0f),
                                        fmaxf(__fsub_rn(iy2, iy1), 0.0f));
                float uni = fmaxf(__fsub_rn(__fadd_rn(pca, ca), inter), 1e-6f);
                if (__fdiv_rn(inter, uni) > IOU_THR) myAlive = false;
            }
            if (lane == j) myAlive = false;
            aliveMask = __ballot(myAlive);
        }
        if (hasInvalid) break;   // sorted: everything after this chunk invalid
    }
    for (int t2 = kc + lane; t2 < 100; t2 += 64) {
        float* dr = out + ((size_t)b * 100 + t2) * 5;
        dr[0] = 0.0f; dr[1] = 0.0f; dr[2] = 0.0f; dr[3] = 0.0f; dr[4] = 0.0f;
        out[(size_t)BATCH * 500 + b * 100 + t2] = -1.0f;
    }
}

extern "C" void kernel_launch(void* const* d_in, const int* in_sizes, int n_in,
                              void* d_out, int out_size, void* d_ws, size_t ws_size,
                              hipStream_t stream) {
    static const int HW5[5] = {36864, 9216, 2304, 576, 144};
    int mc[5], mb[5], mt[5];
    bool found = false;
    for (int hyp = 0; hyp < 3 && !found; ++hyp) {
        bool ok = true;
        int tc[5], tb[5], tt[5];
        for (int l = 0; l < 5 && ok; ++l) {
            int ic, ib, it;
            if (hyp == 0)      { ic = 3*l;   ib = 3*l+1; it = 3*l+2; } // dict order
            else if (hyp == 1) { ic = l;     ib = 5+l;   it = 10+l;  } // arg order
            else               { ib = l;     ic = 5+l;   it = 10+l;  } // sorted keys
            if (in_sizes[ic] != 2*BATCH*HW5[l] ||
                in_sizes[ib] != 4*BATCH*HW5[l] ||
                in_sizes[it] != 1*BATCH*HW5[l]) ok = false;
            tc[l]=ic; tb[l]=ib; tt[l]=it;
        }
        if (ok) { for (int l=0;l<5;++l){mc[l]=tc[l];mb[l]=tb[l];mt[l]=tt[l];} found = true; }
    }
    if (!found) { for (int l=0;l<5;++l){mc[l]=3*l;mb[l]=3*l+1;mt[l]=3*l+2;} }

    P5 C, Bb, T;
    for (int l = 0; l < 5; ++l) {
        C.p[l]  = (const float*)d_in[mc[l]];
        Bb.p[l] = (const float*)d_in[mb[l]];
        T.p[l]  = (const float*)d_in[mt[l]];
    }

    // Workspace layout (6.53 MB; boxes/scores reuse wkeys region after
    // k_select has finished reading it — stream-ordered):
    uint8_t* w = (uint8_t*)d_ws;
    float*          wkeys    = (float*)w;                        // 6,285,312 B
    float*          boxes_g  = (float*)w;                        // 1,904,640 B (reuse)
    float*          scores_g = (float*)(w + 2097152);            //   952,320 B (reuse)
    unsigned short* slots_g  = (unsigned short*)(w + 6291456);   //   238,080 B

    k_select<<<dim3(160),  dim3(512), 0, stream>>>(C, T, wkeys, slots_g);
    k_decode<<<dim3((BATCH*M_TOT + 255)/256), dim3(256), 0, stream>>>(
        C, Bb, T, slots_g, boxes_g, scores_g);
    k_nms   <<<dim3(BATCH), dim3(1024), 0, stream>>>(boxes_g, scores_g, (float*)d_out);
}

// Round 18
// 302.239 us; speedup vs baseline: 47.7735x; 1.0401x over previous
//
#include <hip/hip_runtime.h>
#include <stdint.h>

#define BATCH 32
#define M_TOT 3720          // 1000+1000+1000+576+144
#define NCAND 7440          // M_TOT * 2 classes
#define NPAD 8192
#define SCORE_THR 0.05f
#define IOU_THR 0.6f
#define RCLIP 4.135166556742356f
#define IMG 1536.0f

__device__ __forceinline__ float sigf(float x) {
    return __fdiv_rn(1.0f, __fadd_rn(1.0f, expf(-x)));
}

struct P5 { const float* p[5]; };

// ---------- K1: register-resident keys + exact top-k rank order ------------
// Keys computed ONCE from inputs (bit-identical math), held in registers for
// all radix passes + compaction. Per-wave histograms kill atomic contention.
template <int NPT>
__device__ __forceinline__ void select_level(
    const float* __restrict__ cls, const float* __restrict__ ctr,
    int b, int hw, int take, unsigned short* __restrict__ slots_out,
    unsigned long long* cu, unsigned* hist,
    unsigned& sh_bin, unsigned& sh_krem, unsigned& sh_cnt)
{
    const int tid = threadIdx.x;
    float kv[NPT];
#pragma unroll
    for (int r = 0; r < NPT; ++r) {
        int i = tid + r * 512;
        if (i < hw) {
            float s0 = sigf(cls[(size_t)(2*b)*hw + i]);
            float s1 = sigf(cls[(size_t)(2*b+1)*hw + i]);
            float sc = sigf(ctr[(size_t)b*hw + i]);
            kv[r] = __fmul_rn(fmaxf(s0, s1), sc);   // > 0 always
        } else {
            kv[r] = -1.0f;
        }
    }

    int n;
    if (hw > 1000) {
        unsigned pref = 0, krem = 1000;
        for (int p = 0; p < 4; ++p) {
            const int shift = 24 - 8 * p;
            for (int z = tid; z < 2048; z += 512) hist[z] = 0;
            __syncthreads();
            unsigned* myh = hist + ((tid >> 6) << 8);   // per-wave histogram
#pragma unroll
            for (int r = 0; r < NPT; ++r) {
                int i = tid + r * 512;
                if (i < hw) {
                    unsigned u = __float_as_uint(kv[r]);
                    bool match = (p == 0) || ((u >> (shift + 8)) == pref);
                    if (match) atomicAdd(&myh[(u >> shift) & 255u], 1u);
                }
            }
            __syncthreads();
            if (tid < 256) {                            // merge 8 wave-hists
                unsigned tot = 0;
#pragma unroll
                for (int w2 = 0; w2 < 8; ++w2) tot += hist[w2 * 256 + tid];
                hist[tid] = tot;                        // same slot this thread read
            }
            __syncthreads();
            if (tid == 0) {
                unsigned c = 0; int bsel = 0; unsigned kr = krem;
                for (int bin = 255; bin >= 0; --bin) {
                    unsigned h = hist[bin];
                    if (c + h >= kr) { bsel = bin; kr -= c; break; }
                    c += h;
                }
                sh_bin = (unsigned)bsel;
                sh_krem = kr;
                sh_cnt = 0;
            }
            __syncthreads();
            pref = (pref << 8) | sh_bin;
            krem = sh_krem;
        }
        const unsigned T = pref;
#pragma unroll
        for (int r = 0; r < NPT; ++r) {
            int i = tid + r * 512;
            if (i < hw) {
                unsigned u = __float_as_uint(kv[r]);
                if (u >= T) {
                    unsigned pos = atomicAdd(&sh_cnt, 1u);
                    if (pos < 2048u)
                        cu[pos] = (((unsigned long long)u) << 20) | (unsigned)(0xFFFFF - i);
                }
            }
        }
        __syncthreads();
        n = (int)sh_cnt; if (n > 2048) n = 2048;
    } else {
#pragma unroll
        for (int r = 0; r < NPT; ++r) {
            int i = tid + r * 512;
            if (i < hw) {
                unsigned u = __float_as_uint(kv[r]);
                cu[i] = (((unsigned long long)u) << 20) | (unsigned)(0xFFFFF - i);
            }
        }
        n = hw;
        __syncthreads();
    }
    // rank-by-count (composite order == value desc, loc asc; entries unique)
    for (int a = tid; a < n; a += 512) {
        unsigned long long ka = cu[a];
        int rank = 0;
        for (int q = 0; q < n; ++q) rank += (cu[q] > ka) ? 1 : 0;
        if (rank < take) {
            unsigned loc = 0xFFFFFu - (unsigned)(ka & 0xFFFFFu);
            slots_out[rank] = (unsigned short)loc;
        }
    }
}

__global__ __launch_bounds__(512) void k_select(P5 CLS, P5 CT,
                                                unsigned short* __restrict__ slots_g) {
    __shared__ unsigned long long cu[2048];   // 16 KB composites
    __shared__ unsigned hist[2048];           //  8 KB: 8 per-wave histograms
    __shared__ unsigned sh_bin, sh_krem, sh_cnt;

    const int HWs[5]  = {36864, 9216, 2304, 576, 144};
    const int MOFF[5] = {0, 1000, 2000, 3000, 3576};

    const int blk = blockIdx.x;        // 0..159
    const int b = blk / 5, l = blk % 5;
    const int hw = HWs[l];
    const int take = (hw < 1000) ? hw : 1000;
    unsigned short* slots_out = slots_g + (size_t)b * M_TOT + MOFF[l];

    if (l == 0)      select_level<72>(CLS.p[0], CT.p[0], b, hw, take, slots_out, cu, hist, sh_bin, sh_krem, sh_cnt);
    else if (l == 1) select_level<18>(CLS.p[1], CT.p[1], b, hw, take, slots_out, cu, hist, sh_bin, sh_krem, sh_cnt);
    else if (l == 2) select_level<5> (CLS.p[2], CT.p[2], b, hw, take, slots_out, cu, hist, sh_bin, sh_krem, sh_cnt);
    else if (l == 3) select_level<2> (CLS.p[3], CT.p[3], b, hw, take, slots_out, cu, hist, sh_bin, sh_krem, sh_cnt);
    else             select_level<1> (CLS.p[4], CT.p[4], b, hw, take, slots_out, cu, hist, sh_bin, sh_krem, sh_cnt);
}

// ---------- K2: decode boxes + candidate scores, wide (unchanged, green) ---
__global__ __launch_bounds__(256) void k_decode(P5 CLS, P5 BB, P5 CT,
                                                const unsigned short* __restrict__ slots_g,
                                                float* __restrict__ boxes_g,
                                                float* __restrict__ scores_g) {
    const int HWs[5]  = {36864, 9216, 2304, 576, 144};
    const int Ws[5]   = {192, 96, 48, 24, 12};
    const int STRs[5] = {8, 16, 32, 64, 128};
    int t = blockIdx.x * blockDim.x + threadIdx.x;
    if (t >= BATCH * M_TOT) return;
    int b = t / M_TOT;
    int m = t - b * M_TOT;
    int l;
    if (m < 1000)      l = 0;
    else if (m < 2000) l = 1;
    else if (m < 3000) l = 2;
    else if (m < 3576) l = 3;
    else               l = 4;
    const int hw = HWs[l], w = Ws[l], stride = STRs[l];
    int loc = slots_g[t];

    float ctv = sigf(CT.p[l][(size_t)b*hw + loc]);
    float sc0 = __fmul_rn(sigf(CLS.p[l][(size_t)(2*b+0)*hw + loc]), ctv);
    float sc1 = __fmul_rn(sigf(CLS.p[l][(size_t)(2*b+1)*hw + loc]), ctv);
    scores_g[(size_t)b * NCAND + 2*m + 0] = (sc0 > SCORE_THR) ? sc0 : -1.0f;
    scores_g[(size_t)b * NCAND + 2*m + 1] = (sc1 > SCORE_THR) ? sc1 : -1.0f;

    int yy = loc / w;
    int xx = loc - yy * w;
    const float* bb = BB.p[l];
    float d0 = bb[(size_t)(4*b+0)*hw + loc];
    float d1 = bb[(size_t)(4*b+1)*hw + loc];
    float d2 = bb[(size_t)(4*b+2)*hw + loc];
    float d3 = bb[(size_t)(4*b+3)*hw + loc];
    float a   = (float)(8 * stride);
    float acx = (float)(xx * stride);
    float acy = (float)(yy * stride);
    float dwv = fminf(fmaxf(d2, -RCLIP), RCLIP);
    float dhv = fminf(fmaxf(d3, -RCLIP), RCLIP);
    float pcx = __fadd_rn(acx, __fmul_rn(d0, a));
    float pcy = __fadd_rn(acy, __fmul_rn(d1, a));
    float pw  = __fmul_rn(a, expf(dwv));
    float ph  = __fmul_rn(a, expf(dhv));
    float* bx = boxes_g + (size_t)t * 4;
    bx[0] = fminf(fmaxf(__fsub_rn(pcx, __fmul_rn(0.5f, pw)), 0.0f), IMG);
    bx[1] = fminf(fmaxf(__fsub_rn(pcy, __fmul_rn(0.5f, ph)), 0.0f), IMG);
    bx[2] = fminf(fmaxf(__fadd_rn(pcx, __fmul_rn(0.5f, pw)), 0.0f), IMG);
    bx[3] = fminf(fmaxf(__fadd_rn(pcy, __fmul_rn(0.5f, ph)), 0.0f), IMG);
}

// ---------- K3: NMS = register-bitonic sort + candidate-parallel scan ------
// (unchanged from green round 17)
__global__ __launch_bounds__(1024) void k_nms(const float* __restrict__ boxes_g,
                                              const float* __restrict__ scores_g,
                                              float* __restrict__ out) {
    __shared__ unsigned long long cu[NPAD];   // 64 KB
    const int b = blockIdx.x, tid = threadIdx.x;

    unsigned long long v[8];
    if (tid < 930) {
        const float4* s4 = (const float4*)(scores_g + (size_t)b * NCAND) + tid * 2;
        float4 a4 = s4[0], c4 = s4[1];
        float ss[8] = {a4.x, a4.y, a4.z, a4.w, c4.x, c4.y, c4.z, c4.w};
#pragma unroll
        for (int r = 0; r < 8; ++r) {
            int i = tid * 8 + r;
            v[r] = (ss[r] > 0.0f)
                ? ((((unsigned long long)(~__float_as_uint(ss[r]))) << 16) | (unsigned)i)
                : ~0ULL;
        }
    } else {
#pragma unroll
        for (int r = 0; r < 8; ++r) v[r] = ~0ULL;
    }

    for (unsigned kk = 2; kk <= NPAD; kk <<= 1) {
        for (unsigned j = kk >> 1; j > 0; j >>= 1) {
            if (j >= 512) {
                __syncthreads();
#pragma unroll
                for (int r = 0; r < 8; ++r) cu[tid * 8 + r] = v[r];
                __syncthreads();
#pragma unroll
                for (int r = 0; r < 8; ++r) {
                    unsigned i = tid * 8 + r;
                    unsigned long long pv = cu[i ^ j];
                    bool up = ((i & kk) == 0);
                    bool lower = ((i & j) == 0);
                    bool keepmin = (lower == up);
                    v[r] = keepmin ? (v[r] < pv ? v[r] : pv)
                                   : (v[r] > pv ? v[r] : pv);
                }
            } else if (j >= 8) {
                unsigned m = j >> 3;
#pragma unroll
                for (int r = 0; r < 8; ++r) {
                    unsigned long long pv = __shfl_xor(v[r], (int)m, 64);
                    unsigned i = tid * 8 + r;
                    bool up = ((i & kk) == 0);
                    bool lower = ((i & j) == 0);
                    bool keepmin = (lower == up);
                    v[r] = keepmin ? (v[r] < pv ? v[r] : pv)
                                   : (v[r] > pv ? v[r] : pv);
                }
            } else {
#pragma unroll
                for (int r = 0; r < 8; ++r) {
                    if ((r & j) == 0) {
                        unsigned i = tid * 8 + r;
                        bool up = ((i & kk) == 0);
                        unsigned long long a = v[r], b2 = v[r | j];
                        if ((a > b2) == up) { v[r] = b2; v[r | j] = a; }
                    }
                }
            }
        }
    }
    __syncthreads();
#pragma unroll
    for (int r = 0; r < 8; ++r) cu[tid * 8 + r] = v[r];
    __syncthreads();

    if (tid >= 64) return;   // wave 0 only; no more barriers

    const int lane = tid;
    const float4* bx4 = (const float4*)(boxes_g + (size_t)b * M_TOT * 4);
    float* keptL = (float*)(cu + NCAND);

    int kc = 0;
    bool done = false;

    for (int base = 0; base < NCAND && kc < 100 && !done; base += 64) {
        unsigned long long e = (base + lane < NCAND) ? cu[base + lane] : ~0ULL;
        bool valid = (e != ~0ULL);
        unsigned myidx = (unsigned)(e & 0xFFFFull);
        float myscore = __uint_as_float(~(unsigned)(e >> 16));
        int myc = (int)(myidx & 1u);
        float bx1 = 0, by1 = 0, bx2 = 0, by2 = 0;
        if (valid) {
            float4 vv = bx4[myidx >> 1];
            bx1 = vv.x; by1 = vv.y; bx2 = vv.z; by2 = vv.w;
        }
        float offv = myc ? (IMG + 1.0f) : 0.0f;
        float ox1 = __fadd_rn(bx1, offv), oy1 = __fadd_rn(by1, offv);
        float ox2 = __fadd_rn(bx2, offv), oy2 = __fadd_rn(by2, offv);
        float ca = __fmul_rn(__fsub_rn(ox2, ox1), __fsub_rn(oy2, oy1));
        float uni_s = fmaxf(__fsub_rn(__fadd_rn(ca, ca), ca), 1e-6f);
        bool mySticky = !(__fdiv_rn(ca, uni_s) > IOU_THR);

        const bool hasInvalid = (__ballot(!valid) != 0ULL);

        bool ov = false;
        if (valid) {
            for (int k = 0; k < kc && !ov; ++k) {
                float px1 = keptL[k*5+0], py1 = keptL[k*5+1];
                float px2 = keptL[k*5+2], py2 = keptL[k*5+3];
                float pa  = keptL[k*5+4];
                float ix1 = fmaxf(px1, ox1), iy1 = fmaxf(py1, oy1);
                float ix2 = fminf(px2, ox2), iy2 = fminf(py2, oy2);
                float inter = __fmul_rn(fmaxf(__fsub_rn(ix2, ix1), 0.0f),
                                        fmaxf(__fsub_rn(iy2, iy1), 0.0f));
                float uni = fmaxf(__fsub_rn(__fadd_rn(pa, ca), inter), 1e-6f);
                ov = (__fdiv_rn(inter, uni) > IOU_THR);
            }
        }
        bool myAlive = valid && !ov;
        unsigned long long aliveMask = __ballot(myAlive);

        while (aliveMask != 0ULL && kc < 100) {
            int j = __ffsll(aliveMask) - 1;
            float pbx1 = __shfl(bx1, j), pby1 = __shfl(by1, j);
            float pbx2 = __shfl(bx2, j), pby2 = __shfl(by2, j);
            float pox1 = __shfl(ox1, j), poy1 = __shfl(oy1, j);
            float pox2 = __shfl(ox2, j), poy2 = __shfl(oy2, j);
            float pca  = __shfl(ca, j);
            float psc  = __shfl(myscore, j);
            int   pc   = __shfl(myc, j);
            int   pst  = __shfl((int)mySticky, j);

            if (pst) {
                for (int t2 = kc + lane; t2 < 100; t2 += 64) {
                    float* dr = out + ((size_t)b * 100 + t2) * 5;
                    dr[0] = pbx1; dr[1] = pby1; dr[2] = pbx2; dr[3] = pby2; dr[4] = psc;
                    out[(size_t)BATCH * 500 + b * 100 + t2] = (float)pc;
                }
                kc = 100;
                done = true;
                break;
            }
            if (lane == 0) {
                float* dr = out + ((size_t)b * 100 + kc) * 5;
                dr[0] = pbx1; dr[1] = pby1; dr[2] = pbx2; dr[3] = pby2; dr[4] = psc;
                out[(size_t)BATCH * 500 + b * 100 + kc] = (float)pc;
                keptL[kc*5+0] = pox1; keptL[kc*5+1] = poy1;
                keptL[kc*5+2] = pox2; keptL[kc*5+3] = poy2;
                keptL[kc*5+4] = pca;
            }
            ++kc;
            if (myAlive && lane > j) {
                float ix1 = fmaxf(pox1, ox1), iy1 = fmaxf(poy1, oy1);
                float ix2 = fminf(pox2, ox2), iy2 = fminf(poy2, oy2);
                float inter = __fmul_rn(fmaxf(__fsub_rn(ix2, ix1), 0.0f),
                                        fmaxf(__fsub_rn(iy2, iy1), 0.0f));
                float uni = fmaxf(__fsub_rn(__fadd_rn(pca, ca), inter), 1e-6f);
                if (__fdiv_rn(inter, uni) > IOU_THR) myAlive = false;
            }
            if (lane == j) myAlive = false;
            aliveMask = __ballot(myAlive);
        }
        if (hasInvalid) break;
    }
    for (int t2 = kc + lane; t2 < 100; t2 += 64) {
        float* dr = out + ((size_t)b * 100 + t2) * 5;
        dr[0] = 0.0f; dr[1] = 0.0f; dr[2] = 0.0f; dr[3] = 0.0f; dr[4] = 0.0f;
        out[(size_t)BATCH * 500 + b * 100 + t2] = -1.0f;
    }
}

extern "C" void kernel_launch(void* const* d_in, const int* in_sizes, int n_in,
                              void* d_out, int out_size, void* d_ws, size_t ws_size,
                              hipStream_t stream) {
    static const int HW5[5] = {36864, 9216, 2304, 576, 144};
    int mc[5], mb[5], mt[5];
    bool found = false;
    for (int hyp = 0; hyp < 3 && !found; ++hyp) {
        bool ok = true;
        int tc[5], tb[5], tt[5];
        for (int l = 0; l < 5 && ok; ++l) {
            int ic, ib, it;
            if (hyp == 0)      { ic = 3*l;   ib = 3*l+1; it = 3*l+2; } // dict order
            else if (hyp == 1) { ic = l;     ib = 5+l;   it = 10+l;  } // arg order
            else               { ib = l;     ic = 5+l;   it = 10+l;  } // sorted keys
            if (in_sizes[ic] != 2*BATCH*HW5[l] ||
                in_sizes[ib] != 4*BATCH*HW5[l] ||
                in_sizes[it] != 1*BATCH*HW5[l]) ok = false;
            tc[l]=ic; tb[l]=ib; tt[l]=it;
        }
        if (ok) { for (int l=0;l<5;++l){mc[l]=tc[l];mb[l]=tb[l];mt[l]=tt[l];} found = true; }
    }
    if (!found) { for (int l=0;l<5;++l){mc[l]=3*l;mb[l]=3*l+1;mt[l]=3*l+2;} }

    P5 C, Bb, T;
    for (int l = 0; l < 5; ++l) {
        C.p[l]  = (const float*)d_in[mc[l]];
        Bb.p[l] = (const float*)d_in[mb[l]];
        T.p[l]  = (const float*)d_in[mt[l]];
    }

    // Workspace layout (no wkeys needed anymore):
    uint8_t* w = (uint8_t*)d_ws;
    float*          boxes_g  = (float*)w;                        // 1,904,640 B
    float*          scores_g = (float*)(w + 2097152);            //   952,320 B
    unsigned short* slots_g  = (unsigned short*)(w + 6291456);   //   238,080 B

    k_select<<<dim3(160),  dim3(512), 0, stream>>>(C, T, slots_g);
    k_decode<<<dim3((BATCH*M_TOT + 255)/256), dim3(256), 0, stream>>>(
        C, Bb, T, slots_g, boxes_g, scores_g);
    k_nms   <<<dim3(BATCH), dim3(1024), 0, stream>>>(boxes_g, scores_g, (float*)d_out);
}

// Round 19
// 236.318 us; speedup vs baseline: 61.0999x; 1.2790x over previous
//
#include <hip/hip_runtime.h>
#include <stdint.h>

#define BATCH 32
#define M_TOT 3720          // 1000+1000+1000+576+144
#define NCAND 7440          // M_TOT * 2 classes
#define NPAD 8192
#define SCORE_THR 0.05f
#define IOU_THR 0.6f
#define RCLIP 4.135166556742356f
#define IMG 1536.0f

__device__ __forceinline__ float sigf(float x) {
    return __fdiv_rn(1.0f, __fadd_rn(1.0f, expf(-x)));
}

struct P5 { const float* p[5]; };

// ---------- K1: register-resident keys + exact top-k rank order ------------
// 1024 threads/block. Keys computed once (bit-identical math), held in regs
// for all radix passes + compaction. Bin selection is a parallel suffix-sum
// with EXACTLY the serial loop's accounting (suf_excl < kr <= suf_incl).
template <int NPT>
__device__ __forceinline__ void select_level(
    const float* __restrict__ cls, const float* __restrict__ ctr,
    int b, int hw, int take, unsigned short* __restrict__ slots_out,
    unsigned long long* cu, unsigned* hist, unsigned* wtot,
    unsigned& sh_bin, unsigned& sh_krem, unsigned& sh_cnt)
{
    const int tid = threadIdx.x;
    float kv[NPT];
#pragma unroll
    for (int r = 0; r < NPT; ++r) {
        int i = tid + r * 1024;
        if (i < hw) {
            float s0 = sigf(cls[(size_t)(2*b)*hw + i]);
            float s1 = sigf(cls[(size_t)(2*b+1)*hw + i]);
            float sc = sigf(ctr[(size_t)b*hw + i]);
            kv[r] = __fmul_rn(fmaxf(s0, s1), sc);   // > 0 always
        } else {
            kv[r] = -1.0f;
        }
    }

    int n;
    if (hw > 1000) {
        unsigned pref = 0, krem = 1000;
        for (int p = 0; p < 4; ++p) {
            const int shift = 24 - 8 * p;
            if (tid < 256) hist[tid] = 0;
            __syncthreads();
#pragma unroll
            for (int r = 0; r < NPT; ++r) {
                int i = tid + r * 1024;
                if (i < hw) {
                    unsigned u = __float_as_uint(kv[r]);
                    bool match = (p == 0) || ((u >> (shift + 8)) == pref);
                    if (match) atomicAdd(&hist[(u >> shift) & 255u], 1u);
                }
            }
            __syncthreads();
            // ---- parallel bin selection (threads 0..255 = waves 0..3) ----
            unsigned h = 0, s = 0;
            if (tid < 256) {
                h = hist[tid];
                s = h;
#pragma unroll
                for (int d = 1; d < 64; d <<= 1) {
                    unsigned o = __shfl_down(s, d);     // from lane+d (higher bin)
                    if ((tid & 63) + d < 64) s += o;
                }
                if ((tid & 63) == 0) wtot[tid >> 6] = s; // wave-total
            }
            __syncthreads();
            if (tid < 256) {
                unsigned hi = 0;
                int wv = tid >> 6;
                for (int w2 = wv + 1; w2 < 4; ++w2) hi += wtot[w2];
                unsigned suf_incl = s + hi;              // sum over bins >= mine
                unsigned suf_excl = suf_incl - h;        // sum over bins >  mine
                if (suf_excl < krem && suf_incl >= krem) {
                    sh_bin = (unsigned)tid;
                    sh_krem = krem - suf_excl;
                    sh_cnt = 0;
                }
            }
            __syncthreads();
            pref = (pref << 8) | sh_bin;
            krem = sh_krem;
        }
        const unsigned T = pref;
#pragma unroll
        for (int r = 0; r < NPT; ++r) {
            int i = tid + r * 1024;
            if (i < hw) {
                unsigned u = __float_as_uint(kv[r]);
                if (u >= T) {
                    unsigned pos = atomicAdd(&sh_cnt, 1u);
                    if (pos < 2048u)
                        cu[pos] = (((unsigned long long)u) << 20) | (unsigned)(0xFFFFF - i);
                }
            }
        }
        __syncthreads();
        n = (int)sh_cnt; if (n > 2048) n = 2048;
    } else {
#pragma unroll
        for (int r = 0; r < NPT; ++r) {
            int i = tid + r * 1024;
            if (i < hw) {
                unsigned u = __float_as_uint(kv[r]);
                cu[i] = (((unsigned long long)u) << 20) | (unsigned)(0xFFFFF - i);
            }
        }
        n = hw;
        __syncthreads();
    }
    // rank-by-count (composite order == value desc, loc asc; entries unique)
    for (int a = tid; a < n; a += 1024) {
        unsigned long long ka = cu[a];
        int rank = 0;
        for (int q = 0; q < n; ++q) rank += (cu[q] > ka) ? 1 : 0;
        if (rank < take) {
            unsigned loc = 0xFFFFFu - (unsigned)(ka & 0xFFFFFu);
            slots_out[rank] = (unsigned short)loc;
        }
    }
}

__global__ __launch_bounds__(1024) void k_select(P5 CLS, P5 CT,
                                                 unsigned short* __restrict__ slots_g) {
    __shared__ unsigned long long cu[2048];   // 16 KB composites
    __shared__ unsigned hist[256];            //  1 KB histogram
    __shared__ unsigned wtot[4];
    __shared__ unsigned sh_bin, sh_krem, sh_cnt;

    const int HWs[5]  = {36864, 9216, 2304, 576, 144};
    const int MOFF[5] = {0, 1000, 2000, 3000, 3576};

    const int blk = blockIdx.x;        // 0..159
    const int b = blk / 5, l = blk % 5;
    const int hw = HWs[l];
    const int take = (hw < 1000) ? hw : 1000;
    unsigned short* slots_out = slots_g + (size_t)b * M_TOT + MOFF[l];

    if (l == 0)      select_level<36>(CLS.p[0], CT.p[0], b, hw, take, slots_out, cu, hist, wtot, sh_bin, sh_krem, sh_cnt);
    else if (l == 1) select_level<9> (CLS.p[1], CT.p[1], b, hw, take, slots_out, cu, hist, wtot, sh_bin, sh_krem, sh_cnt);
    else if (l == 2) select_level<3> (CLS.p[2], CT.p[2], b, hw, take, slots_out, cu, hist, wtot, sh_bin, sh_krem, sh_cnt);
    else if (l == 3) select_level<1> (CLS.p[3], CT.p[3], b, hw, take, slots_out, cu, hist, wtot, sh_bin, sh_krem, sh_cnt);
    else             select_level<1> (CLS.p[4], CT.p[4], b, hw, take, slots_out, cu, hist, wtot, sh_bin, sh_krem, sh_cnt);
}

// ---------- K2: decode boxes + candidate scores, wide (unchanged, green) ---
__global__ __launch_bounds__(256) void k_decode(P5 CLS, P5 BB, P5 CT,
                                                const unsigned short* __restrict__ slots_g,
                                                float* __restrict__ boxes_g,
                                                float* __restrict__ scores_g) {
    const int HWs[5]  = {36864, 9216, 2304, 576, 144};
    const int Ws[5]   = {192, 96, 48, 24, 12};
    const int STRs[5] = {8, 16, 32, 64, 128};
    int t = blockIdx.x * blockDim.x + threadIdx.x;
    if (t >= BATCH * M_TOT) return;
    int b = t / M_TOT;
    int m = t - b * M_TOT;
    int l;
    if (m < 1000)      l = 0;
    else if (m < 2000) l = 1;
    else if (m < 3000) l = 2;
    else if (m < 3576) l = 3;
    else               l = 4;
    const int hw = HWs[l], w = Ws[l], stride = STRs[l];
    int loc = slots_g[t];

    float ctv = sigf(CT.p[l][(size_t)b*hw + loc]);
    float sc0 = __fmul_rn(sigf(CLS.p[l][(size_t)(2*b+0)*hw + loc]), ctv);
    float sc1 = __fmul_rn(sigf(CLS.p[l][(size_t)(2*b+1)*hw + loc]), ctv);
    scores_g[(size_t)b * NCAND + 2*m + 0] = (sc0 > SCORE_THR) ? sc0 : -1.0f;
    scores_g[(size_t)b * NCAND + 2*m + 1] = (sc1 > SCORE_THR) ? sc1 : -1.0f;

    int yy = loc / w;
    int xx = loc - yy * w;
    const float* bb = BB.p[l];
    float d0 = bb[(size_t)(4*b+0)*hw + loc];
    float d1 = bb[(size_t)(4*b+1)*hw + loc];
    float d2 = bb[(size_t)(4*b+2)*hw + loc];
    float d3 = bb[(size_t)(4*b+3)*hw + loc];
    float a   = (float)(8 * stride);
    float acx = (float)(xx * stride);
    float acy = (float)(yy * stride);
    float dwv = fminf(fmaxf(d2, -RCLIP), RCLIP);
    float dhv = fminf(fmaxf(d3, -RCLIP), RCLIP);
    float pcx = __fadd_rn(acx, __fmul_rn(d0, a));
    float pcy = __fadd_rn(acy, __fmul_rn(d1, a));
    float pw  = __fmul_rn(a, expf(dwv));
    float ph  = __fmul_rn(a, expf(dhv));
    float* bx = boxes_g + (size_t)t * 4;
    bx[0] = fminf(fmaxf(__fsub_rn(pcx, __fmul_rn(0.5f, pw)), 0.0f), IMG);
    bx[1] = fminf(fmaxf(__fsub_rn(pcy, __fmul_rn(0.5f, ph)), 0.0f), IMG);
    bx[2] = fminf(fmaxf(__fadd_rn(pcx, __fmul_rn(0.5f, pw)), 0.0f), IMG);
    bx[3] = fminf(fmaxf(__fadd_rn(pcy, __fmul_rn(0.5f, ph)), 0.0f), IMG);
}

// ---------- K3: NMS = register-bitonic sort + candidate-parallel scan ------
// (unchanged from green round 18)
__global__ __launch_bounds__(1024) void k_nms(const float* __restrict__ boxes_g,
                                              const float* __restrict__ scores_g,
                                              float* __restrict__ out) {
    __shared__ unsigned long long cu[NPAD];   // 64 KB
    const int b = blockIdx.x, tid = threadIdx.x;

    unsigned long long v[8];
    if (tid < 930) {
        const float4* s4 = (const float4*)(scores_g + (size_t)b * NCAND) + tid * 2;
        float4 a4 = s4[0], c4 = s4[1];
        float ss[8] = {a4.x, a4.y, a4.z, a4.w, c4.x, c4.y, c4.z, c4.w};
#pragma unroll
        for (int r = 0; r < 8; ++r) {
            int i = tid * 8 + r;
            v[r] = (ss[r] > 0.0f)
                ? ((((unsigned long long)(~__float_as_uint(ss[r]))) << 16) | (unsigned)i)
                : ~0ULL;
        }
    } else {
#pragma unroll
        for (int r = 0; r < 8; ++r) v[r] = ~0ULL;
    }

    for (unsigned kk = 2; kk <= NPAD; kk <<= 1) {
        for (unsigned j = kk >> 1; j > 0; j >>= 1) {
            if (j >= 512) {
                __syncthreads();
#pragma unroll
                for (int r = 0; r < 8; ++r) cu[tid * 8 + r] = v[r];
                __syncthreads();
#pragma unroll
                for (int r = 0; r < 8; ++r) {
                    unsigned i = tid * 8 + r;
                    unsigned long long pv = cu[i ^ j];
                    bool up = ((i & kk) == 0);
                    bool lower = ((i & j) == 0);
                    bool keepmin = (lower == up);
                    v[r] = keepmin ? (v[r] < pv ? v[r] : pv)
                                   : (v[r] > pv ? v[r] : pv);
                }
            } else if (j >= 8) {
                unsigned m = j >> 3;
#pragma unroll
                for (int r = 0; r < 8; ++r) {
                    unsigned long long pv = __shfl_xor(v[r], (int)m, 64);
                    unsigned i = tid * 8 + r;
                    bool up = ((i & kk) == 0);
                    bool lower = ((i & j) == 0);
                    bool keepmin = (lower == up);
                    v[r] = keepmin ? (v[r] < pv ? v[r] : pv)
                                   : (v[r] > pv ? v[r] : pv);
                }
            } else {
#pragma unroll
                for (int r = 0; r < 8; ++r) {
                    if ((r & j) == 0) {
                        unsigned i = tid * 8 + r;
                        bool up = ((i & kk) == 0);
                        unsigned long long a = v[r], b2 = v[r | j];
                        if ((a > b2) == up) { v[r] = b2; v[r | j] = a; }
                    }
                }
            }
        }
    }
    __syncthreads();
#pragma unroll
    for (int r = 0; r < 8; ++r) cu[tid * 8 + r] = v[r];
    __syncthreads();

    if (tid >= 64) return;   // wave 0 only; no more barriers

    const int lane = tid;
    const float4* bx4 = (const float4*)(boxes_g + (size_t)b * M_TOT * 4);
    float* keptL = (float*)(cu + NCAND);

    int kc = 0;
    bool done = false;

    for (int base = 0; base < NCAND && kc < 100 && !done; base += 64) {
        unsigned long long e = (base + lane < NCAND) ? cu[base + lane] : ~0ULL;
        bool valid = (e != ~0ULL);
        unsigned myidx = (unsigned)(e & 0xFFFFull);
        float myscore = __uint_as_float(~(unsigned)(e >> 16));
        int myc = (int)(myidx & 1u);
        float bx1 = 0, by1 = 0, bx2 = 0, by2 = 0;
        if (valid) {
            float4 vv = bx4[myidx >> 1];
            bx1 = vv.x; by1 = vv.y; bx2 = vv.z; by2 = vv.w;
        }
        float offv = myc ? (IMG + 1.0f) : 0.0f;
        float ox1 = __fadd_rn(bx1, offv), oy1 = __fadd_rn(by1, offv);
        float ox2 = __fadd_rn(bx2, offv), oy2 = __fadd_rn(by2, offv);
        float ca = __fmul_rn(__fsub_rn(ox2, ox1), __fsub_rn(oy2, oy1));
        float uni_s = fmaxf(__fsub_rn(__fadd_rn(ca, ca), ca), 1e-6f);
        bool mySticky = !(__fdiv_rn(ca, uni_s) > IOU_THR);

        const bool hasInvalid = (__ballot(!valid) != 0ULL);

        bool ov = false;
        if (valid) {
            for (int k = 0; k < kc && !ov; ++k) {
                float px1 = keptL[k*5+0], py1 = keptL[k*5+1];
                float px2 = keptL[k*5+2], py2 = keptL[k*5+3];
                float pa  = keptL[k*5+4];
                float ix1 = fmaxf(px1, ox1), iy1 = fmaxf(py1, oy1);
                float ix2 = fminf(px2, ox2), iy2 = fminf(py2, oy2);
                float inter = __fmul_rn(fmaxf(__fsub_rn(ix2, ix1), 0.0f),
                                        fmaxf(__fsub_rn(iy2, iy1), 0.0f));
                float uni = fmaxf(__fsub_rn(__fadd_rn(pa, ca), inter), 1e-6f);
                ov = (__fdiv_rn(inter, uni) > IOU_THR);
            }
        }
        bool myAlive = valid && !ov;
        unsigned long long aliveMask = __ballot(myAlive);

        while (aliveMask != 0ULL && kc < 100) {
            int j = __ffsll(aliveMask) - 1;
            float pbx1 = __shfl(bx1, j), pby1 = __shfl(by1, j);
            float pbx2 = __shfl(bx2, j), pby2 = __shfl(by2, j);
            float pox1 = __shfl(ox1, j), poy1 = __shfl(oy1, j);
            float pox2 = __shfl(ox2, j), poy2 = __shfl(oy2, j);
            float pca  = __shfl(ca, j);
            float psc  = __shfl(myscore, j);
            int   pc   = __shfl(myc, j);
            int   pst  = __shfl((int)mySticky, j);

            if (pst) {
                for (int t2 = kc + lane; t2 < 100; t2 += 64) {
                    float* dr = out + ((size_t)b * 100 + t2) * 5;
                    dr[0] = pbx1; dr[1] = pby1; dr[2] = pbx2; dr[3] = pby2; dr[4] = psc;
                    out[(size_t)BATCH * 500 + b * 100 + t2] = (float)pc;
                }
                kc = 100;
                done = true;
                break;
            }
            if (lane == 0) {
                float* dr = out + ((size_t)b * 100 + kc) * 5;
                dr[0] = pbx1; dr[1] = pby1; dr[2] = pbx2; dr[3] = pby2; dr[4] = psc;
                out[(size_t)BATCH * 500 + b * 100 + kc] = (float)pc;
                keptL[kc*5+0] = pox1; keptL[kc*5+1] = poy1;
                keptL[kc*5+2] = pox2; keptL[kc*5+3] = poy2;
                keptL[kc*5+4] = pca;
            }
            ++kc;
            if (myAlive && lane > j) {
                float ix1 = fmaxf(pox1, ox1), iy1 = fmaxf(poy1, oy1);
                float ix2 = fminf(pox2, ox2), iy2 = fminf(poy2, oy2);
                float inter = __fmul_rn(fmaxf(__fsub_rn(ix2, ix1), 0.0f),
                                        fmaxf(__fsub_rn(iy2, iy1), 0.0f));
                float uni = fmaxf(__fsub_rn(__fadd_rn(pca, ca), inter), 1e-6f);
                if (__fdiv_rn(inter, uni) > IOU_THR) myAlive = false;
            }
            if (lane == j) myAlive = false;
            aliveMask = __ballot(myAlive);
        }
        if (hasInvalid) break;
    }
    for (int t2 = kc + lane; t2 < 100; t2 += 64) {
        float* dr = out + ((size_t)b * 100 + t2) * 5;
        dr[0] = 0.0f; dr[1] = 0.0f; dr[2] = 0.0f; dr[3] = 0.0f; dr[4] = 0.0f;
        out[(size_t)BATCH * 500 + b * 100 + t2] = -1.0f;
    }
}

extern "C" void kernel_launch(void* const* d_in, const int* in_sizes, int n_in,
                              void* d_out, int out_size, void* d_ws, size_t ws_size,
                              hipStream_t stream) {
    static const int HW5[5] = {36864, 9216, 2304, 576, 144};
    int mc[5], mb[5], mt[5];
    bool found = false;
    for (int hyp = 0; hyp < 3 && !found; ++hyp) {
        bool ok = true;
        int tc[5], tb[5], tt[5];
        for (int l = 0; l < 5 && ok; ++l) {
            int ic, ib, it;
            if (hyp == 0)      { ic = 3*l;   ib = 3*l+1; it = 3*l+2; } // dict order
            else if (hyp == 1) { ic = l;     ib = 5+l;   it = 10+l;  } // arg order
            else               { ib = l;     ic = 5+l;   it = 10+l;  } // sorted keys
            if (in_sizes[ic] != 2*BATCH*HW5[l] ||
                in_sizes[ib] != 4*BATCH*HW5[l] ||
                in_sizes[it] != 1*BATCH*HW5[l]) ok = false;
            tc[l]=ic; tb[l]=ib; tt[l]=it;
        }
        if (ok) { for (int l=0;l<5;++l){mc[l]=tc[l];mb[l]=tb[l];mt[l]=tt[l];} found = true; }
    }
    if (!found) { for (int l=0;l<5;++l){mc[l]=3*l;mb[l]=3*l+1;mt[l]=3*l+2;} }

    P5 C, Bb, T;
    for (int l = 0; l < 5; ++l) {
        C.p[l]  = (const float*)d_in[mc[l]];
        Bb.p[l] = (const float*)d_in[mb[l]];
        T.p[l]  = (const float*)d_in[mt[l]];
    }

    uint8_t* w = (uint8_t*)d_ws;
    float*          boxes_g  = (float*)w;                        // 1,904,640 B
    float*          scores_g = (float*)(w + 2097152);            //   952,320 B
    unsigned short* slots_g  = (unsigned short*)(w + 6291456);   //   238,080 B

    k_select<<<dim3(160),  dim3(1024), 0, stream>>>(C, T, slots_g);
    k_decode<<<dim3((BATCH*M_TOT + 255)/256), dim3(256), 0, stream>>>(
        C, Bb, T, slots_g, boxes_g, scores_g);
    k_nms   <<<dim3(BATCH), dim3(1024), 0, stream>>>(boxes_g, scores_g, (float*)d_out);
}